// Round 6
// baseline (254.879 us; speedup 1.0000x reference)
//
#include <hip/hip_runtime.h>
#include <hip/hip_bf16.h>

#define B_ 64
#define J_ 2048
#define K_ 32
#define D_ 16
#define KD 512
#define CHB 128      // k_B j-chunks (spart partials)
#define JCB 16       // j's per k_B chunk
#define JCA 2        // j's per k_A block

typedef __attribute__((ext_vector_type(8))) short short8v;   // 8 bf16 (4 VGPR)
typedef __attribute__((ext_vector_type(4))) float f32x4;     // 4 f32 acc

__device__ __forceinline__ float bf2f(unsigned int bits16) {
  unsigned int u = bits16 << 16;
  return __builtin_bit_cast(float, u);
}
__device__ __forceinline__ unsigned int f2bf(float f) {
  unsigned int u = __builtin_bit_cast(unsigned int, f);
  u = u + 0x7fffu + ((u >> 16) & 1u);   // round-to-nearest-even
  return u >> 16;
}
__device__ __forceinline__ short8v mk_frag(unsigned int d0, unsigned int d1) {
  uint4 t = make_uint4(d0, d1, 0u, 0u);        // k-slots 4..7 zero
  return __builtin_bit_cast(short8v, t);
}

// ---------------- prep: WB[j][k][d][i] = bf16(W[k][j][d][i]);  XT[j][b][i] = bf16(x[b][j][i])
__global__ __launch_bounds__(256) void k_prep(const float* __restrict__ inp,
                                              const float* __restrict__ W,
                                              unsigned short* __restrict__ WB,
                                              unsigned short* __restrict__ XT) {
  const size_t tid = (size_t)blockIdx.x * 256 + threadIdx.x;
  const size_t stride = (size_t)gridDim.x * 256;
  for (size_t g8 = tid; g8 < (size_t)J_ * K_ * 32; g8 += stride) {
    const size_t o = g8 * 8;
    const int j = (int)(o >> 13), k = (int)((o >> 8) & 31), di = (int)(o & 255);
    const float* src = W + ((size_t)k * J_ + j) * 256 + di;
    const float4 a = *(const float4*)src;
    const float4 b = *(const float4*)(src + 4);
    uint4 pk;
    pk.x = f2bf(a.x) | (f2bf(a.y) << 16);
    pk.y = f2bf(a.z) | (f2bf(a.w) << 16);
    pk.z = f2bf(b.x) | (f2bf(b.y) << 16);
    pk.w = f2bf(b.z) | (f2bf(b.w) << 16);
    *(uint4*)(WB + o) = pk;
  }
  for (size_t g8 = tid; g8 < (size_t)J_ * B_ * 2; g8 += stride) {
    const size_t o = g8 * 8;
    const int j = (int)(o >> 10), b = (int)((o >> 4) & 63), i0 = (int)(o & 15);
    const float* src = inp + ((size_t)b * J_ + j) * 16 + i0;
    const float4 a = *(const float4*)src;
    const float4 c = *(const float4*)(src + 4);
    uint4 pk;
    pk.x = f2bf(a.x) | (f2bf(a.y) << 16);
    pk.y = f2bf(a.z) | (f2bf(a.w) << 16);
    pk.z = f2bf(c.x) | (f2bf(c.y) << 16);
    pk.w = f2bf(c.z) | (f2bf(c.w) << 16);
    *(uint4*)(XT + o) = pk;
  }
}

// ---------------- k_A: c[b][j][k] = softmax_k(osum . u_hat), u via MFMA in-regs.
// Block = 2 j's, 4 waves = 4 b-groups of 16 (b = wave*16 + (lane&15)).
// k streamed in 2 halves of 16 (os slice 32 VGPR at a time); e kept packed bf16.
template <int WRITEC>
__global__ __launch_bounds__(256) void k_A(const unsigned short* __restrict__ XT,
                                           const unsigned short* __restrict__ WB,
                                           const unsigned short* __restrict__ osum_bf,
                                           float* __restrict__ cB,
                                           float* __restrict__ outp) {
  const int jb = blockIdx.x;                     // j = jb*JCA + jc
  const int t = threadIdx.x;
  const int wave = t >> 6, lane = t & 63;
  const int g = lane >> 4, r = lane & 15;
  const int b = wave * 16 + r;

  __shared__ float cbuf[WRITEC ? JCA * B_ * 33 : 4];

  // x fragments for both j's (hoisted; B-frag col = b, k-slots = i)
  uint2 xv[JCA];
#pragma unroll
  for (int jc = 0; jc < JCA; ++jc)
    xv[jc] = *(const uint2*)(XT + ((size_t)(jb * JCA + jc) * 64 + b) * 16 + 4 * g);

  float S[JCA] = {0.f, 0.f};
  unsigned int e_pk[JCA][16];                    // bf16-packed e; dword d <-> k=2d,2d+1

#pragma unroll
  for (int half = 0; half < 2; ++half) {
    // osum slice for k in [16h, 16h+16), layout [k][b][d]: contiguous 512B wave-read
    uint2 os_pk[16];
#pragma unroll
    for (int kk = 0; kk < 16; ++kk)
      os_pk[kk] = *(const uint2*)(osum_bf + ((size_t)(half * 16 + kk) * 64 + b) * 16 + 4 * g);

#pragma unroll
    for (int jc = 0; jc < JCA; ++jc) {
      const int j = jb * JCA + jc;
      const unsigned short* wj =
          WB + (size_t)j * 8192 + (size_t)(half * 16) * 256 + r * 16 + 4 * g;
      const short8v bfr = mk_frag(xv[jc].x, xv[jc].y);
      float elo = 0.f;
#pragma unroll
      for (int kk = 0; kk < 16; ++kk) {
        const uint2 wv = *(const uint2*)(wj + kk * 256);    // A-frag: W[k] rows d, cols i
        const f32x4 u = __builtin_amdgcn_mfma_f32_16x16x32_bf16(
            mk_frag(wv.x, wv.y), bfr, (f32x4){0.f, 0.f, 0.f, 0.f}, 0, 0, 0);
        float pp;
        pp = u[0] * bf2f(os_pk[kk].x & 0xffffu);
        pp = fmaf(u[1], bf2f(os_pk[kk].x >> 16), pp);
        pp = fmaf(u[2], bf2f(os_pk[kk].y & 0xffffu), pp);
        pp = fmaf(u[3], bf2f(os_pk[kk].y >> 16), pp);
        pp += __shfl_xor(pp, 16);
        pp += __shfl_xor(pp, 32);      // full dot over d; replicated across g
        const float e = __expf(pp);    // logits O(+-3): skip max-subtract (shift-inv)
        S[jc] += e;
        if (kk & 1)
          e_pk[jc][half * 8 + (kk >> 1)] = f2bf(elo) | (f2bf(e) << 16);
        else
          elo = e;
      }
    }
  }

  // epilogue: scale by 1/S, store c (g==0 slice; c replicated across g)
#pragma unroll
  for (int jc = 0; jc < JCA; ++jc) {
    const int j = jb * JCA + jc;
    const float rS = __builtin_amdgcn_rcpf(S[jc]);
    if (g == 0) {
      float* cp = cB + ((size_t)j * 64 + b) * 32;
#pragma unroll
      for (int h = 0; h < 8; ++h) {
        const unsigned int d0 = e_pk[jc][2 * h], d1 = e_pk[jc][2 * h + 1];
        *(float4*)(cp + 4 * h) =
            make_float4(bf2f(d0 & 0xffffu) * rS, bf2f(d0 >> 16) * rS,
                        bf2f(d1 & 0xffffu) * rS, bf2f(d1 >> 16) * rS);
      }
      if constexpr (WRITEC) {
        float* cb = &cbuf[(jc * 64 + b) * 33];
#pragma unroll
        for (int h = 0; h < 16; ++h) {
          cb[2 * h] = bf2f(e_pk[jc][h] & 0xffffu) * rS;
          cb[2 * h + 1] = bf2f(e_pk[jc][h] >> 16) * rS;
        }
      }
    }
  }

  if constexpr (WRITEC) {
    __syncthreads();
#pragma unroll
    for (int it = 0; it < 8; ++it) {
      const int row = it * 256 + t;     // (b2,k2) over 64x32
      const int b2 = row >> 5, k2 = row & 31;
      const float v0 = cbuf[b2 * 33 + k2];
      const float v1 = cbuf[(64 + b2) * 33 + k2];
      *(float2*)(outp + ((size_t)b2 * K_ + k2) * 2064 + 16 + jb * JCA) = make_float2(v0, v1);
    }
  }
}

// ---------------- k_B: s[b][kd] partials via MFMA with c folded into B-frag.
template <int CMODE>
__global__ __launch_bounds__(256) void k_B(const unsigned short* __restrict__ XT,
                                           const unsigned short* __restrict__ WB,
                                           const float* __restrict__ cB,
                                           float* __restrict__ spart) {
  const int x = blockIdx.x;
  const int ch = x >> 5, k = x & 31;
  const int t = threadIdx.x;
  const int wave = t >> 6, lane = t & 63;
  const int g = lane >> 4, r = lane & 15;
  const int b = wave * 16 + r;
  const int j0 = ch * JCB;

  const unsigned short* wp = WB + ((size_t)j0 * 32 + k) * 256 + r * 16 + 4 * g;
  const unsigned short* xp = XT + ((size_t)j0 * 64 + b) * 16 + 4 * g;
  const float* cp = cB + ((size_t)j0 * 64 + b) * 32 + k;

  f32x4 acc = {0.f, 0.f, 0.f, 0.f};
#pragma unroll 4
  for (int jc = 0; jc < JCB; ++jc) {
    const uint2 wv = *(const uint2*)(wp + jc * 8192);
    const uint2 xv = *(const uint2*)(xp + jc * 1024);
    short8v bfr;
    if constexpr (CMODE == 1) {
      const float c = cp[jc * 2048];
      const unsigned int p0 = f2bf(bf2f(xv.x & 0xffffu) * c) |
                              (f2bf(bf2f(xv.x >> 16) * c) << 16);
      const unsigned int p1 = f2bf(bf2f(xv.y & 0xffffu) * c) |
                              (f2bf(bf2f(xv.y >> 16) * c) << 16);
      bfr = mk_frag(p0, p1);
    } else {
      bfr = mk_frag(xv.x, xv.y);
    }
    acc = __builtin_amdgcn_mfma_f32_16x16x32_bf16(mk_frag(wv.x, wv.y), bfr, acc, 0, 0, 0);
  }
  const float sc = (CMODE == 0) ? (1.f / 32.f) : 1.f;
  // C layout: col = b (lane&15), row = d = 4g + reg  ->  16B contiguous store
  *(float4*)(spart + (((size_t)b * CHB + ch) * 32 + k) * 16 + 4 * g) =
      make_float4(acc[0] * sc, acc[1] * sc, acc[2] * sc, acc[3] * sc);
}

// ---------------- squash: reduce spart -> s, squash -> o; f32 osum + bf16 [k][b][d] mirror.
__global__ __launch_bounds__(256) void k_squash(const float* __restrict__ spart,
                                                float* __restrict__ osum,
                                                unsigned short* __restrict__ osum_bf,
                                                float* __restrict__ outp,
                                                int first, int final_) {
  const int t = threadIdx.x;
  const int wave = t >> 6, lane = t & 63;
  const int gw = blockIdx.x * 4 + wave;   // 0..B_*K_-1
  const int b = gw >> 5, k = gw & 31;
  const int d = lane & 15, pg = lane >> 4;
  float s = 0.f;
  for (int p = pg; p < CHB; p += 4)
    s += spart[(((size_t)b * CHB + p) * 32 + k) * 16 + d];
  s += __shfl_xor(s, 16);
  s += __shfl_xor(s, 32);
  float ss = s * s;
  ss += __shfl_xor(ss, 1); ss += __shfl_xor(ss, 2);
  ss += __shfl_xor(ss, 4); ss += __shfl_xor(ss, 8);
  const float scale = (ss / (1.f + ss)) * rsqrtf(ss + 1e-7f);
  const float ov = scale * s;
  if (final_) {
    if (lane < 16) outp[((size_t)b * K_ + k) * 2064 + d] = ov;
  } else {
    const float prev = first ? 0.f : osum[b * KD + k * 16 + d];
    const float ns = prev + ov;
    const float partner = __shfl_xor(ns, 1);
    if (lane < 16) {
      osum[b * KD + k * 16 + d] = ns;
      if (!(lane & 1)) {
        const unsigned int pk = f2bf(ns) | (f2bf(partner) << 16);
        *(unsigned int*)(osum_bf + ((size_t)k * 64 + b) * 16 + d) = pk;
      }
    }
  }
}

extern "C" void kernel_launch(void* const* d_in, const int* in_sizes, int n_in,
                              void* d_out, int out_size, void* d_ws, size_t ws_size,
                              hipStream_t stream) {
  const float* inp = (const float*)d_in[0];   // [64,2048,16]
  const float* W   = (const float*)d_in[1];   // [32,2048,16,16]
  float* outp = (float*)d_out;                // [64,32,2064]
  char* ws = (char*)d_ws;
  // ws: WB 32M | XT 4M | cB 16M | spart 16M | osum 128K | osum_bf 64K  (~68.2 MiB)
  unsigned short* WB = (unsigned short*)ws;
  unsigned short* XT = (unsigned short*)(ws + (size_t)33554432);
  float* cB    = (float*)(ws + (size_t)33554432 + 4194304);
  float* spart = (float*)(ws + (size_t)33554432 + 4194304 + 16777216);
  float* osum  = (float*)(ws + (size_t)33554432 + 4194304 + 16777216 + 16777216);
  unsigned short* osum_bf =
      (unsigned short*)(ws + (size_t)33554432 + 4194304 + 16777216 + 16777216 + 131072);

  k_prep<<<2048, 256, 0, stream>>>(inp, W, WB, XT);
  // iter 0: c = 1/32
  k_B<0><<<CHB * K_, 256, 0, stream>>>(XT, WB, nullptr, spart);
  k_squash<<<B_ * K_ / 4, 256, 0, stream>>>(spart, osum, osum_bf, outp, 1, 0);
  // iter 1
  k_A<0><<<J_ / JCA, 256, 0, stream>>>(XT, WB, osum_bf, cB, nullptr);
  k_B<1><<<CHB * K_, 256, 0, stream>>>(XT, WB, cB, spart);
  k_squash<<<B_ * K_ / 4, 256, 0, stream>>>(spart, osum, osum_bf, outp, 0, 0);
  // iter 2 (final): c to outp, o to outp
  k_A<1><<<J_ / JCA, 256, 0, stream>>>(XT, WB, osum_bf, cB, outp);
  k_B<1><<<CHB * K_, 256, 0, stream>>>(XT, WB, cB, spart);
  k_squash<<<B_ * K_ / 4, 256, 0, stream>>>(spart, osum, osum_bf, outp, 0, 1);
}

// Round 7
// 247.724 us; speedup vs baseline: 1.0289x; 1.0289x over previous
//
#include <hip/hip_runtime.h>
#include <hip/hip_bf16.h>

#define B_ 64
#define J_ 2048
#define K_ 32
#define D_ 16
#define KD 512
#define CHB 128      // k_B j-chunks (spart partials)
#define JCB 16       // j's per k_B chunk
#define JCA 2        // j's per k_A block

typedef __attribute__((ext_vector_type(8))) short short8v;   // 8 bf16 (4 VGPR)
typedef __attribute__((ext_vector_type(4))) float f32x4;     // 4 f32 acc

__device__ __forceinline__ float bf2f(unsigned int bits16) {
  unsigned int u = bits16 << 16;
  return __builtin_bit_cast(float, u);
}
__device__ __forceinline__ unsigned int f2bf(float f) {
  unsigned int u = __builtin_bit_cast(unsigned int, f);
  u = u + 0x7fffu + ((u >> 16) & 1u);   // round-to-nearest-even
  return u >> 16;
}
__device__ __forceinline__ short8v mk_frag(unsigned int d0, unsigned int d1) {
  uint4 t = make_uint4(d0, d1, 0u, 0u);        // k-slots 4..7 zero
  return __builtin_bit_cast(short8v, t);
}

// ---------------- prep: WB[j][k][d][i] = bf16(W[k][j][d][i]);  XT[j][b][i] = bf16(x[b][j][i])
__global__ __launch_bounds__(256) void k_prep(const float* __restrict__ inp,
                                              const float* __restrict__ W,
                                              unsigned short* __restrict__ WB,
                                              unsigned short* __restrict__ XT) {
  const size_t tid = (size_t)blockIdx.x * 256 + threadIdx.x;
  const size_t stride = (size_t)gridDim.x * 256;
  for (size_t g8 = tid; g8 < (size_t)J_ * K_ * 32; g8 += stride) {
    const size_t o = g8 * 8;
    const int j = (int)(o >> 13), k = (int)((o >> 8) & 31), di = (int)(o & 255);
    const float* src = W + ((size_t)k * J_ + j) * 256 + di;
    const float4 a = *(const float4*)src;
    const float4 b = *(const float4*)(src + 4);
    uint4 pk;
    pk.x = f2bf(a.x) | (f2bf(a.y) << 16);
    pk.y = f2bf(a.z) | (f2bf(a.w) << 16);
    pk.z = f2bf(b.x) | (f2bf(b.y) << 16);
    pk.w = f2bf(b.z) | (f2bf(b.w) << 16);
    *(uint4*)(WB + o) = pk;
  }
  for (size_t g8 = tid; g8 < (size_t)J_ * B_ * 2; g8 += stride) {
    const size_t o = g8 * 8;
    const int j = (int)(o >> 10), b = (int)((o >> 4) & 63), i0 = (int)(o & 15);
    const float* src = inp + ((size_t)b * J_ + j) * 16 + i0;
    const float4 a = *(const float4*)src;
    const float4 c = *(const float4*)(src + 4);
    uint4 pk;
    pk.x = f2bf(a.x) | (f2bf(a.y) << 16);
    pk.y = f2bf(a.z) | (f2bf(a.w) << 16);
    pk.z = f2bf(c.x) | (f2bf(c.y) << 16);
    pk.w = f2bf(c.z) | (f2bf(c.w) << 16);
    *(uint4*)(XT + o) = pk;
  }
}

// ---------------- k_A: raw logits p[j][b][k] = osum[b,k,:] . u_hat[b,j,k,:].
// Block = 2 j's, 4 waves = 4 b-groups of 16 (b = wave*16 + (lane&15)).
// No softmax state: one MFMA + dot + 2 shuffles per (j,k); p banked 4-wide, stored f32.
__global__ __launch_bounds__(256) void k_A(const unsigned short* __restrict__ XT,
                                           const unsigned short* __restrict__ WB,
                                           const unsigned short* __restrict__ osum_bf,
                                           float* __restrict__ pB) {
  const int jb = blockIdx.x;                     // j = jb*JCA + jc
  const int t = threadIdx.x;
  const int wave = t >> 6, lane = t & 63;
  const int g = lane >> 4, r = lane & 15;
  const int b = wave * 16 + r;

  uint2 xv[JCA];
#pragma unroll
  for (int jc = 0; jc < JCA; ++jc)
    xv[jc] = *(const uint2*)(XT + ((size_t)(jb * JCA + jc) * 64 + b) * 16 + 4 * g);

  const unsigned short* osb = osum_bf + b * 16 + 4 * g;              // + k*1024
  const unsigned short* wb0 = WB + (size_t)jb * JCA * 8192 + r * 16 + 4 * g;  // + jc*8192 + k*256

  float p4[JCA][4];
#pragma unroll
  for (int k = 0; k < 32; ++k) {
    const uint2 os = *(const uint2*)(osb + (size_t)k * 1024);
#pragma unroll
    for (int jc = 0; jc < JCA; ++jc) {
      const uint2 wv = *(const uint2*)(wb0 + jc * 8192 + k * 256);
      const f32x4 u = __builtin_amdgcn_mfma_f32_16x16x32_bf16(
          mk_frag(wv.x, wv.y), mk_frag(xv[jc].x, xv[jc].y),
          (f32x4){0.f, 0.f, 0.f, 0.f}, 0, 0, 0);
      float pp;
      pp = u[0] * bf2f(os.x & 0xffffu);
      pp = fmaf(u[1], bf2f(os.x >> 16), pp);
      pp = fmaf(u[2], bf2f(os.y & 0xffffu), pp);
      pp = fmaf(u[3], bf2f(os.y >> 16), pp);
      pp += __shfl_xor(pp, 16);
      pp += __shfl_xor(pp, 32);          // full dot over d; replicated across lanes
      p4[jc][k & 3] = pp;
    }
    if ((k & 3) == 3 && g == 0) {
#pragma unroll
      for (int jc = 0; jc < JCA; ++jc)
        *(float4*)(pB + ((size_t)(jb * JCA + jc) * 64 + b) * 32 + (k & ~3)) =
            make_float4(p4[jc][0], p4[jc][1], p4[jc][2], p4[jc][3]);
    }
  }
}

// ---------------- k_soft: in-place softmax over k (contiguous 32 floats per (j,b)).
__global__ __launch_bounds__(256) void k_soft(float* __restrict__ cB) {
  const size_t id = (size_t)blockIdx.x * 256 + threadIdx.x;   // (j,b) pair
  float* cp = cB + id * 32;
  float4 v[8];
#pragma unroll
  for (int h = 0; h < 8; ++h) v[h] = *(const float4*)(cp + 4 * h);
  float S = 0.f;
#pragma unroll
  for (int h = 0; h < 8; ++h) {
    // logits O(+-4): skip max-subtraction (softmax shift-invariant; validated r1-r6)
    v[h].x = __expf(v[h].x); v[h].y = __expf(v[h].y);
    v[h].z = __expf(v[h].z); v[h].w = __expf(v[h].w);
    S += (v[h].x + v[h].y) + (v[h].z + v[h].w);
  }
  const float rS = __builtin_amdgcn_rcpf(S);
#pragma unroll
  for (int h = 0; h < 8; ++h) {
    v[h].x *= rS; v[h].y *= rS; v[h].z *= rS; v[h].w *= rS;
    *(float4*)(cp + 4 * h) = v[h];
  }
}

// ---------------- k_cout: c[j][b][k] -> outp[b][k][16+j] via LDS transpose tile.
__global__ __launch_bounds__(256) void k_cout(const float* __restrict__ cB,
                                              float* __restrict__ outp) {
  const int bx = blockIdx.x;
  const int b = bx >> 4, j0 = (bx & 15) * 128;
  const int t = threadIdx.x;
  __shared__ float lds[128][33];
#pragma unroll
  for (int pass = 0; pass < 16; ++pass) {
    const int jj = pass * 8 + (t >> 5), k = t & 31;
    lds[jj][k] = cB[((size_t)(j0 + jj) * 64 + b) * 32 + k];
  }
  __syncthreads();
#pragma unroll
  for (int pass = 0; pass < 16; ++pass) {
    const int k = pass * 2 + (t >> 7), jj = t & 127;
    outp[((size_t)b * K_ + k) * 2064 + 16 + j0 + jj] = lds[jj][k];
  }
}

// ---------------- k_B: s[b][kd] partials via MFMA with c folded into B-frag.
template <int CMODE>
__global__ __launch_bounds__(256) void k_B(const unsigned short* __restrict__ XT,
                                           const unsigned short* __restrict__ WB,
                                           const float* __restrict__ cB,
                                           float* __restrict__ spart) {
  const int x = blockIdx.x;
  const int ch = x >> 5, k = x & 31;
  const int t = threadIdx.x;
  const int wave = t >> 6, lane = t & 63;
  const int g = lane >> 4, r = lane & 15;
  const int b = wave * 16 + r;
  const int j0 = ch * JCB;

  const unsigned short* wp = WB + ((size_t)j0 * 32 + k) * 256 + r * 16 + 4 * g;
  const unsigned short* xp = XT + ((size_t)j0 * 64 + b) * 16 + 4 * g;
  const float* cp = cB + ((size_t)j0 * 64 + b) * 32 + k;

  f32x4 acc = {0.f, 0.f, 0.f, 0.f};
#pragma unroll 4
  for (int jc = 0; jc < JCB; ++jc) {
    const uint2 wv = *(const uint2*)(wp + jc * 8192);
    const uint2 xv = *(const uint2*)(xp + jc * 1024);
    short8v bfr;
    if constexpr (CMODE == 1) {
      const float c = cp[jc * 2048];
      const unsigned int p0 = f2bf(bf2f(xv.x & 0xffffu) * c) |
                              (f2bf(bf2f(xv.x >> 16) * c) << 16);
      const unsigned int p1 = f2bf(bf2f(xv.y & 0xffffu) * c) |
                              (f2bf(bf2f(xv.y >> 16) * c) << 16);
      bfr = mk_frag(p0, p1);
    } else {
      bfr = mk_frag(xv.x, xv.y);
    }
    acc = __builtin_amdgcn_mfma_f32_16x16x32_bf16(mk_frag(wv.x, wv.y), bfr, acc, 0, 0, 0);
  }
  const float sc = (CMODE == 0) ? (1.f / 32.f) : 1.f;
  // C layout: col = b (lane&15), row = d = 4g + reg  ->  16B contiguous store
  *(float4*)(spart + (((size_t)b * CHB + ch) * 32 + k) * 16 + 4 * g) =
      make_float4(acc[0] * sc, acc[1] * sc, acc[2] * sc, acc[3] * sc);
}

// ---------------- squash: reduce spart -> s, squash -> o; f32 osum + bf16 [k][b][d] mirror.
__global__ __launch_bounds__(256) void k_squash(const float* __restrict__ spart,
                                                float* __restrict__ osum,
                                                unsigned short* __restrict__ osum_bf,
                                                float* __restrict__ outp,
                                                int first, int final_) {
  const int t = threadIdx.x;
  const int wave = t >> 6, lane = t & 63;
  const int gw = blockIdx.x * 4 + wave;   // 0..B_*K_-1
  const int b = gw >> 5, k = gw & 31;
  const int d = lane & 15, pg = lane >> 4;
  float s = 0.f;
  for (int p = pg; p < CHB; p += 4)
    s += spart[(((size_t)b * CHB + p) * 32 + k) * 16 + d];
  s += __shfl_xor(s, 16);
  s += __shfl_xor(s, 32);
  float ss = s * s;
  ss += __shfl_xor(ss, 1); ss += __shfl_xor(ss, 2);
  ss += __shfl_xor(ss, 4); ss += __shfl_xor(ss, 8);
  const float scale = (ss / (1.f + ss)) * rsqrtf(ss + 1e-7f);
  const float ov = scale * s;
  if (final_) {
    if (lane < 16) outp[((size_t)b * K_ + k) * 2064 + d] = ov;
  } else {
    const float prev = first ? 0.f : osum[b * KD + k * 16 + d];
    const float ns = prev + ov;
    const float partner = __shfl_xor(ns, 1);
    if (lane < 16) {
      osum[b * KD + k * 16 + d] = ns;
      if (!(lane & 1)) {
        const unsigned int pk = f2bf(ns) | (f2bf(partner) << 16);
        *(unsigned int*)(osum_bf + ((size_t)k * 64 + b) * 16 + d) = pk;
      }
    }
  }
}

extern "C" void kernel_launch(void* const* d_in, const int* in_sizes, int n_in,
                              void* d_out, int out_size, void* d_ws, size_t ws_size,
                              hipStream_t stream) {
  const float* inp = (const float*)d_in[0];   // [64,2048,16]
  const float* W   = (const float*)d_in[1];   // [32,2048,16,16]
  float* outp = (float*)d_out;                // [64,32,2064]
  char* ws = (char*)d_ws;
  // ws: WB 32M | XT 4M | cB 16M | spart 16M | osum 128K | osum_bf 64K  (~68.2 MiB)
  unsigned short* WB = (unsigned short*)ws;
  unsigned short* XT = (unsigned short*)(ws + (size_t)33554432);
  float* cB    = (float*)(ws + (size_t)33554432 + 4194304);
  float* spart = (float*)(ws + (size_t)33554432 + 4194304 + 16777216);
  float* osum  = (float*)(ws + (size_t)33554432 + 4194304 + 16777216 + 16777216);
  unsigned short* osum_bf =
      (unsigned short*)(ws + (size_t)33554432 + 4194304 + 16777216 + 16777216 + 131072);

  k_prep<<<2048, 256, 0, stream>>>(inp, W, WB, XT);
  // iter 0: c = 1/32
  k_B<0><<<CHB * K_, 256, 0, stream>>>(XT, WB, nullptr, spart);
  k_squash<<<B_ * K_ / 4, 256, 0, stream>>>(spart, osum, osum_bf, outp, 1, 0);
  // iter 1
  k_A<<<J_ / JCA, 256, 0, stream>>>(XT, WB, osum_bf, cB);
  k_soft<<<J_ * B_ / 256, 256, 0, stream>>>(cB);
  k_B<1><<<CHB * K_, 256, 0, stream>>>(XT, WB, cB, spart);
  k_squash<<<B_ * K_ / 4, 256, 0, stream>>>(spart, osum, osum_bf, outp, 0, 0);
  // iter 2 (final)
  k_A<<<J_ / JCA, 256, 0, stream>>>(XT, WB, osum_bf, cB);
  k_soft<<<J_ * B_ / 256, 256, 0, stream>>>(cB);
  k_cout<<<B_ * 16, 256, 0, stream>>>(cB, outp);
  k_B<1><<<CHB * K_, 256, 0, stream>>>(XT, WB, cB, spart);
  k_squash<<<B_ * K_ / 4, 256, 0, stream>>>(spart, osum, osum_bf, outp, 0, 1);
}

// Round 8
// 228.092 us; speedup vs baseline: 1.1174x; 1.0861x over previous
//
#include <hip/hip_runtime.h>
#include <hip/hip_bf16.h>

#define B_ 64
#define J_ 2048
#define K_ 32
#define D_ 16
#define KD 512
#define CHB 128      // k_B j-chunks (spart partials)
#define JCB 16       // j's per k_B chunk
#define JCA 2        // j's per k_A block

typedef __attribute__((ext_vector_type(8))) short short8v;   // 8 bf16 (4 VGPR)
typedef __attribute__((ext_vector_type(4))) float f32x4;     // 4 f32 acc

__device__ __forceinline__ float bf2f(unsigned int bits16) {
  unsigned int u = bits16 << 16;
  return __builtin_bit_cast(float, u);
}
__device__ __forceinline__ unsigned int f2bf(float f) {
  unsigned int u = __builtin_bit_cast(unsigned int, f);
  u = u + 0x7fffu + ((u >> 16) & 1u);   // round-to-nearest-even
  return u >> 16;
}
__device__ __forceinline__ short8v mk_frag(unsigned int d0, unsigned int d1) {
  uint4 t = make_uint4(d0, d1, 0u, 0u);        // k-slots 4..7 zero
  return __builtin_bit_cast(short8v, t);
}
__device__ __forceinline__ short8v mk_frag4(unsigned int d0, unsigned int d1,
                                            unsigned int d2, unsigned int d3) {
  uint4 t = make_uint4(d0, d1, d2, d3);        // slots 0-3 = j0, 4-7 = j1
  return __builtin_bit_cast(short8v, t);
}

// ---------------- prep: WB[j][k][d][i] = bf16(W[k][j][d][i]);  XT[j][b][i] = bf16(x[b][j][i])
__global__ __launch_bounds__(256) void k_prep(const float* __restrict__ inp,
                                              const float* __restrict__ W,
                                              unsigned short* __restrict__ WB,
                                              unsigned short* __restrict__ XT) {
  const size_t tid = (size_t)blockIdx.x * 256 + threadIdx.x;
  const size_t stride = (size_t)gridDim.x * 256;
  for (size_t g8 = tid; g8 < (size_t)J_ * K_ * 32; g8 += stride) {
    const size_t o = g8 * 8;
    const int j = (int)(o >> 13), k = (int)((o >> 8) & 31), di = (int)(o & 255);
    const float* src = W + ((size_t)k * J_ + j) * 256 + di;
    const float4 a = *(const float4*)src;
    const float4 b = *(const float4*)(src + 4);
    uint4 pk;
    pk.x = f2bf(a.x) | (f2bf(a.y) << 16);
    pk.y = f2bf(a.z) | (f2bf(a.w) << 16);
    pk.z = f2bf(b.x) | (f2bf(b.y) << 16);
    pk.w = f2bf(b.z) | (f2bf(b.w) << 16);
    *(uint4*)(WB + o) = pk;
  }
  for (size_t g8 = tid; g8 < (size_t)J_ * B_ * 2; g8 += stride) {
    const size_t o = g8 * 8;
    const int j = (int)(o >> 10), b = (int)((o >> 4) & 63), i0 = (int)(o & 15);
    const float* src = inp + ((size_t)b * J_ + j) * 16 + i0;
    const float4 a = *(const float4*)src;
    const float4 c = *(const float4*)(src + 4);
    uint4 pk;
    pk.x = f2bf(a.x) | (f2bf(a.y) << 16);
    pk.y = f2bf(a.z) | (f2bf(a.w) << 16);
    pk.z = f2bf(c.x) | (f2bf(c.y) << 16);
    pk.w = f2bf(c.z) | (f2bf(c.w) << 16);
    *(uint4*)(XT + o) = pk;
  }
}

// ---------------- k_A: raw logits p[j][b][k] = osum[b,k,:] . u_hat[b,j,k,:].
// Block = 2 j's, 4 waves = 4 b-groups of 16 (b = wave*16 + (lane&15)).
// k processed in 4 groups of 8: 24 loads issued together, then 16 MFMAs + dots.
__global__ __launch_bounds__(256) void k_A(const unsigned short* __restrict__ XT,
                                           const unsigned short* __restrict__ WB,
                                           const unsigned short* __restrict__ osum_bf,
                                           float* __restrict__ pB) {
  const int jb = blockIdx.x;                     // j = jb*JCA + jc
  const int t = threadIdx.x;
  const int wave = t >> 6, lane = t & 63;
  const int g = lane >> 4, r = lane & 15;
  const int b = wave * 16 + r;

  uint2 xv[JCA];
#pragma unroll
  for (int jc = 0; jc < JCA; ++jc)
    xv[jc] = *(const uint2*)(XT + ((size_t)(jb * JCA + jc) * 64 + b) * 16 + 4 * g);
  const short8v xf0 = mk_frag(xv[0].x, xv[0].y);
  const short8v xf1 = mk_frag(xv[1].x, xv[1].y);

  const unsigned short* osb = osum_bf + b * 16 + 4 * g;              // + k*1024
  const unsigned short* wb0 = WB + (size_t)jb * JCA * 8192 + r * 16 + 4 * g;  // + jc*8192 + k*256

  float p4[JCA][4];
#pragma unroll
  for (int kg = 0; kg < 4; ++kg) {
    // ---- batch-issue loads for 8 k's
    uint2 os[8], w0[8], w1[8];
#pragma unroll
    for (int kk = 0; kk < 8; ++kk) {
      const int k = kg * 8 + kk;
      os[kk] = *(const uint2*)(osb + (size_t)k * 1024);
      w0[kk] = *(const uint2*)(wb0 + (size_t)k * 256);
      w1[kk] = *(const uint2*)(wb0 + 8192 + (size_t)k * 256);
    }
    // ---- compute
#pragma unroll
    for (int kk = 0; kk < 8; ++kk) {
      const int k = kg * 8 + kk;
      const f32x4 u0 = __builtin_amdgcn_mfma_f32_16x16x32_bf16(
          mk_frag(w0[kk].x, w0[kk].y), xf0, (f32x4){0.f, 0.f, 0.f, 0.f}, 0, 0, 0);
      const f32x4 u1 = __builtin_amdgcn_mfma_f32_16x16x32_bf16(
          mk_frag(w1[kk].x, w1[kk].y), xf1, (f32x4){0.f, 0.f, 0.f, 0.f}, 0, 0, 0);
      const float o0 = bf2f(os[kk].x & 0xffffu), o1 = bf2f(os[kk].x >> 16);
      const float o2 = bf2f(os[kk].y & 0xffffu), o3 = bf2f(os[kk].y >> 16);
      float pp0 = u0[0] * o0;
      pp0 = fmaf(u0[1], o1, pp0); pp0 = fmaf(u0[2], o2, pp0); pp0 = fmaf(u0[3], o3, pp0);
      float pp1 = u1[0] * o0;
      pp1 = fmaf(u1[1], o1, pp1); pp1 = fmaf(u1[2], o2, pp1); pp1 = fmaf(u1[3], o3, pp1);
      pp0 += __shfl_xor(pp0, 16); pp0 += __shfl_xor(pp0, 32);
      pp1 += __shfl_xor(pp1, 16); pp1 += __shfl_xor(pp1, 32);
      p4[0][k & 3] = pp0;
      p4[1][k & 3] = pp1;
      if ((k & 3) == 3 && g == 0) {
#pragma unroll
        for (int jc = 0; jc < JCA; ++jc)
          *(float4*)(pB + ((size_t)(jb * JCA + jc) * 64 + b) * 32 + (k & ~3)) =
              make_float4(p4[jc][0], p4[jc][1], p4[jc][2], p4[jc][3]);
      }
    }
  }
}

// ---------------- k_soft: in-place softmax over k (contiguous 32 floats per (j,b)).
__global__ __launch_bounds__(256) void k_soft(float* __restrict__ cB) {
  const size_t id = (size_t)blockIdx.x * 256 + threadIdx.x;   // (j,b) pair
  float* cp = cB + id * 32;
  float4 v[8];
#pragma unroll
  for (int h = 0; h < 8; ++h) v[h] = *(const float4*)(cp + 4 * h);
  float S = 0.f;
#pragma unroll
  for (int h = 0; h < 8; ++h) {
    // logits O(+-4): skip max-subtraction (softmax shift-invariant; validated r1-r7)
    v[h].x = __expf(v[h].x); v[h].y = __expf(v[h].y);
    v[h].z = __expf(v[h].z); v[h].w = __expf(v[h].w);
    S += (v[h].x + v[h].y) + (v[h].z + v[h].w);
  }
  const float rS = __builtin_amdgcn_rcpf(S);
#pragma unroll
  for (int h = 0; h < 8; ++h) {
    v[h].x *= rS; v[h].y *= rS; v[h].z *= rS; v[h].w *= rS;
    *(float4*)(cp + 4 * h) = v[h];
  }
}

// ---------------- k_cout: c[j][b][k] -> outp[b][k][16+j] via LDS transpose tile.
__global__ __launch_bounds__(256) void k_cout(const float* __restrict__ cB,
                                              float* __restrict__ outp) {
  const int bx = blockIdx.x;
  const int b = bx >> 4, j0 = (bx & 15) * 128;
  const int t = threadIdx.x;
  __shared__ float lds[128][33];
#pragma unroll
  for (int pass = 0; pass < 16; ++pass) {
    const int jj = pass * 8 + (t >> 5), k = t & 31;
    lds[jj][k] = cB[((size_t)(j0 + jj) * 64 + b) * 32 + k];
  }
  __syncthreads();
#pragma unroll
  for (int pass = 0; pass < 16; ++pass) {
    const int k = pass * 2 + (t >> 7), jj = t & 127;
    outp[((size_t)b * K_ + k) * 2064 + 16 + j0 + jj] = lds[jj][k];
  }
}

// ---------------- k_B: s[b][kd] partials via MFMA, c folded into B-frag.
// All loads hoisted (one latency window), j-pairs packed into MFMA slots 4-7.
template <int CMODE>
__global__ __launch_bounds__(256) void k_B(const unsigned short* __restrict__ XT,
                                           const unsigned short* __restrict__ WB,
                                           const float* __restrict__ cB,
                                           float* __restrict__ spart) {
  const int x = blockIdx.x;
  const int ch = x >> 5, k = x & 31;
  const int t = threadIdx.x;
  const int wave = t >> 6, lane = t & 63;
  const int g = lane >> 4, r = lane & 15;
  const int b = wave * 16 + r;
  const int j0 = ch * JCB;

  const unsigned short* wp = WB + ((size_t)j0 * 32 + k) * 256 + r * 16 + 4 * g;
  const unsigned short* xp = XT + ((size_t)j0 * 64 + b) * 16 + 4 * g;
  const float* cp = cB + ((size_t)j0 * 64 + b) * 32 + k;

  // ---- hoist ALL loads: 48 independent VMEM ops in flight together
  uint2 wv[JCB], xv[JCB];
  float cv[JCB];
#pragma unroll
  for (int jc = 0; jc < JCB; ++jc) wv[jc] = *(const uint2*)(wp + (size_t)jc * 8192);
#pragma unroll
  for (int jc = 0; jc < JCB; ++jc) xv[jc] = *(const uint2*)(xp + (size_t)jc * 1024);
  if constexpr (CMODE == 1) {
#pragma unroll
    for (int jc = 0; jc < JCB; ++jc) cv[jc] = cp[(size_t)jc * 2048];
  }

  // ---- compute: 8 j-pair MFMAs (slots 0-3 = even j, 4-7 = odd j; same map A and B)
  f32x4 acc = {0.f, 0.f, 0.f, 0.f};
#pragma unroll
  for (int jp = 0; jp < 8; ++jp) {
    const int ja = 2 * jp, jb2 = 2 * jp + 1;
    const short8v af = mk_frag4(wv[ja].x, wv[ja].y, wv[jb2].x, wv[jb2].y);
    short8v bf;
    if constexpr (CMODE == 1) {
      const float ca = cv[ja], cb = cv[jb2];
      const unsigned int p0 = f2bf(bf2f(xv[ja].x & 0xffffu) * ca) |
                              (f2bf(bf2f(xv[ja].x >> 16) * ca) << 16);
      const unsigned int p1 = f2bf(bf2f(xv[ja].y & 0xffffu) * ca) |
                              (f2bf(bf2f(xv[ja].y >> 16) * ca) << 16);
      const unsigned int p2 = f2bf(bf2f(xv[jb2].x & 0xffffu) * cb) |
                              (f2bf(bf2f(xv[jb2].x >> 16) * cb) << 16);
      const unsigned int p3 = f2bf(bf2f(xv[jb2].y & 0xffffu) * cb) |
                              (f2bf(bf2f(xv[jb2].y >> 16) * cb) << 16);
      bf = mk_frag4(p0, p1, p2, p3);
    } else {
      bf = mk_frag4(xv[ja].x, xv[ja].y, xv[jb2].x, xv[jb2].y);
    }
    acc = __builtin_amdgcn_mfma_f32_16x16x32_bf16(af, bf, acc, 0, 0, 0);
  }
  const float sc = (CMODE == 0) ? (1.f / 32.f) : 1.f;
  // C layout: col = b (lane&15), row = d = 4g + reg  ->  16B contiguous store
  *(float4*)(spart + (((size_t)b * CHB + ch) * 32 + k) * 16 + 4 * g) =
      make_float4(acc[0] * sc, acc[1] * sc, acc[2] * sc, acc[3] * sc);
}

// ---------------- squash: reduce spart -> s, squash -> o; f32 osum + bf16 [k][b][d] mirror.
__global__ __launch_bounds__(256) void k_squash(const float* __restrict__ spart,
                                                float* __restrict__ osum,
                                                unsigned short* __restrict__ osum_bf,
                                                float* __restrict__ outp,
                                                int first, int final_) {
  const int t = threadIdx.x;
  const int wave = t >> 6, lane = t & 63;
  const int gw = blockIdx.x * 4 + wave;   // 0..B_*K_-1
  const int b = gw >> 5, k = gw & 31;
  const int d = lane & 15, pg = lane >> 4;
  float s = 0.f;
  for (int p = pg; p < CHB; p += 4)
    s += spart[(((size_t)b * CHB + p) * 32 + k) * 16 + d];
  s += __shfl_xor(s, 16);
  s += __shfl_xor(s, 32);
  float ss = s * s;
  ss += __shfl_xor(ss, 1); ss += __shfl_xor(ss, 2);
  ss += __shfl_xor(ss, 4); ss += __shfl_xor(ss, 8);
  const float scale = (ss / (1.f + ss)) * rsqrtf(ss + 1e-7f);
  const float ov = scale * s;
  if (final_) {
    if (lane < 16) outp[((size_t)b * K_ + k) * 2064 + d] = ov;
  } else {
    const float prev = first ? 0.f : osum[b * KD + k * 16 + d];
    const float ns = prev + ov;
    const float partner = __shfl_xor(ns, 1);
    if (lane < 16) {
      osum[b * KD + k * 16 + d] = ns;
      if (!(lane & 1)) {
        const unsigned int pk = f2bf(ns) | (f2bf(partner) << 16);
        *(unsigned int*)(osum_bf + ((size_t)k * 64 + b) * 16 + d) = pk;
      }
    }
  }
}

extern "C" void kernel_launch(void* const* d_in, const int* in_sizes, int n_in,
                              void* d_out, int out_size, void* d_ws, size_t ws_size,
                              hipStream_t stream) {
  const float* inp = (const float*)d_in[0];   // [64,2048,16]
  const float* W   = (const float*)d_in[1];   // [32,2048,16,16]
  float* outp = (float*)d_out;                // [64,32,2064]
  char* ws = (char*)d_ws;
  // ws: WB 32M | XT 4M | cB 16M | spart 16M | osum 128K | osum_bf 64K  (~68.2 MiB)
  unsigned short* WB = (unsigned short*)ws;
  unsigned short* XT = (unsigned short*)(ws + (size_t)33554432);
  float* cB    = (float*)(ws + (size_t)33554432 + 4194304);
  float* spart = (float*)(ws + (size_t)33554432 + 4194304 + 16777216);
  float* osum  = (float*)(ws + (size_t)33554432 + 4194304 + 16777216 + 16777216);
  unsigned short* osum_bf =
      (unsigned short*)(ws + (size_t)33554432 + 4194304 + 16777216 + 16777216 + 131072);

  k_prep<<<2048, 256, 0, stream>>>(inp, W, WB, XT);
  // iter 0: c = 1/32
  k_B<0><<<CHB * K_, 256, 0, stream>>>(XT, WB, nullptr, spart);
  k_squash<<<B_ * K_ / 4, 256, 0, stream>>>(spart, osum, osum_bf, outp, 1, 0);
  // iter 1
  k_A<<<J_ / JCA, 256, 0, stream>>>(XT, WB, osum_bf, cB);
  k_soft<<<J_ * B_ / 256, 256, 0, stream>>>(cB);
  k_B<1><<<CHB * K_, 256, 0, stream>>>(XT, WB, cB, spart);
  k_squash<<<B_ * K_ / 4, 256, 0, stream>>>(spart, osum, osum_bf, outp, 0, 0);
  // iter 2 (final)
  k_A<<<J_ / JCA, 256, 0, stream>>>(XT, WB, osum_bf, cB);
  k_soft<<<J_ * B_ / 256, 256, 0, stream>>>(cB);
  k_cout<<<B_ * 16, 256, 0, stream>>>(cB, outp);
  k_B<1><<<CHB * K_, 256, 0, stream>>>(XT, WB, cB, spart);
  k_squash<<<B_ * K_ / 4, 256, 0, stream>>>(spart, osum, osum_bf, outp, 0, 1);
}

// Round 9
// 198.540 us; speedup vs baseline: 1.2838x; 1.1488x over previous
//
#include <hip/hip_runtime.h>
#include <hip/hip_bf16.h>

#define B_ 64
#define J_ 2048
#define K_ 32
#define D_ 16
#define KD 512
#define CHB 128      // k_B j-chunks (spart partials)
#define JCB 16       // j's per k_B chunk
#define JCA 2        // j's per k_A block

typedef __attribute__((ext_vector_type(8))) short short8v;   // 8 bf16 (4 VGPR)
typedef __attribute__((ext_vector_type(4))) float f32x4;     // 4 f32 acc

__device__ __forceinline__ float bf2f(unsigned int bits16) {
  unsigned int u = bits16 << 16;
  return __builtin_bit_cast(float, u);
}
__device__ __forceinline__ unsigned int f2bf(float f) {
  unsigned int u = __builtin_bit_cast(unsigned int, f);
  u = u + 0x7fffu + ((u >> 16) & 1u);   // round-to-nearest-even
  return u >> 16;
}
__device__ __forceinline__ short8v mk_frag(unsigned int d0, unsigned int d1) {
  uint4 t = make_uint4(d0, d1, 0u, 0u);        // k-slots 4..7 zero
  return __builtin_bit_cast(short8v, t);
}
__device__ __forceinline__ short8v mk_frag4(unsigned int d0, unsigned int d1,
                                            unsigned int d2, unsigned int d3) {
  uint4 t = make_uint4(d0, d1, d2, d3);        // slots 0-3 = j0, 4-7 = j1
  return __builtin_bit_cast(short8v, t);
}

// ---------------- prep: WB[j][k][d][i] = bf16(W[k][j][d][i]);  XT[j][b][i] = bf16(x[b][j][i])
__global__ __launch_bounds__(256) void k_prep(const float* __restrict__ inp,
                                              const float* __restrict__ W,
                                              unsigned short* __restrict__ WB,
                                              unsigned short* __restrict__ XT) {
  const size_t tid = (size_t)blockIdx.x * 256 + threadIdx.x;
  const size_t stride = (size_t)gridDim.x * 256;
  for (size_t g8 = tid; g8 < (size_t)J_ * K_ * 32; g8 += stride) {
    const size_t o = g8 * 8;
    const int j = (int)(o >> 13), k = (int)((o >> 8) & 31), di = (int)(o & 255);
    const float* src = W + ((size_t)k * J_ + j) * 256 + di;
    const float4 a = *(const float4*)src;
    const float4 b = *(const float4*)(src + 4);
    uint4 pk;
    pk.x = f2bf(a.x) | (f2bf(a.y) << 16);
    pk.y = f2bf(a.z) | (f2bf(a.w) << 16);
    pk.z = f2bf(b.x) | (f2bf(b.y) << 16);
    pk.w = f2bf(b.z) | (f2bf(b.w) << 16);
    *(uint4*)(WB + o) = pk;
  }
  for (size_t g8 = tid; g8 < (size_t)J_ * B_ * 2; g8 += stride) {
    const size_t o = g8 * 8;
    const int j = (int)(o >> 10), b = (int)((o >> 4) & 63), i0 = (int)(o & 15);
    const float* src = inp + ((size_t)b * J_ + j) * 16 + i0;
    const float4 a = *(const float4*)src;
    const float4 c = *(const float4*)(src + 4);
    uint4 pk;
    pk.x = f2bf(a.x) | (f2bf(a.y) << 16);
    pk.y = f2bf(a.z) | (f2bf(a.w) << 16);
    pk.z = f2bf(c.x) | (f2bf(c.y) << 16);
    pk.w = f2bf(c.z) | (f2bf(c.w) << 16);
    *(uint4*)(XT + o) = pk;
  }
}

// ---------------- k_A: raw logits pT[j][k][b] = osum[b,k,:] . u_hat[b,j,k,:].
// Block = 2 j's, 4 waves = 4 b-groups of 16 (b = wave*16 + (lane&15)).
// k in 4 groups of 8: 24 loads batch-issued (fit in 128-VGPR budget), then 16 MFMAs.
__global__ __launch_bounds__(256, 4) void k_A(const unsigned short* __restrict__ XT,
                                              const unsigned short* __restrict__ WB,
                                              const unsigned short* __restrict__ osum_bf,
                                              float* __restrict__ pT) {
  const int jb = blockIdx.x;                     // j = jb*JCA + jc
  const int t = threadIdx.x;
  const int wave = t >> 6, lane = t & 63;
  const int g = lane >> 4, r = lane & 15;
  const int b = wave * 16 + r;

  uint2 xv[JCA];
#pragma unroll
  for (int jc = 0; jc < JCA; ++jc)
    xv[jc] = *(const uint2*)(XT + ((size_t)(jb * JCA + jc) * 64 + b) * 16 + 4 * g);
  const short8v xf0 = mk_frag(xv[0].x, xv[0].y);
  const short8v xf1 = mk_frag(xv[1].x, xv[1].y);

  const unsigned short* osb = osum_bf + b * 16 + 4 * g;              // + k*1024
  const unsigned short* wb0 = WB + (size_t)jb * JCA * 8192 + r * 16 + 4 * g;  // + jc*8192 + k*256

  float p4[JCA][4];
#pragma unroll
  for (int kg = 0; kg < 4; ++kg) {
    // ---- batch-issue loads for 8 k's (one latency window)
    uint2 os[8], w0[8], w1[8];
#pragma unroll
    for (int kk = 0; kk < 8; ++kk) {
      const int k = kg * 8 + kk;
      os[kk] = *(const uint2*)(osb + (size_t)k * 1024);
      w0[kk] = *(const uint2*)(wb0 + (size_t)k * 256);
      w1[kk] = *(const uint2*)(wb0 + 8192 + (size_t)k * 256);
    }
    // ---- compute
#pragma unroll
    for (int kk = 0; kk < 8; ++kk) {
      const int k = kg * 8 + kk;
      const f32x4 u0 = __builtin_amdgcn_mfma_f32_16x16x32_bf16(
          mk_frag(w0[kk].x, w0[kk].y), xf0, (f32x4){0.f, 0.f, 0.f, 0.f}, 0, 0, 0);
      const f32x4 u1 = __builtin_amdgcn_mfma_f32_16x16x32_bf16(
          mk_frag(w1[kk].x, w1[kk].y), xf1, (f32x4){0.f, 0.f, 0.f, 0.f}, 0, 0, 0);
      const float o0 = bf2f(os[kk].x & 0xffffu), o1 = bf2f(os[kk].x >> 16);
      const float o2 = bf2f(os[kk].y & 0xffffu), o3 = bf2f(os[kk].y >> 16);
      float pp0 = u0[0] * o0;
      pp0 = fmaf(u0[1], o1, pp0); pp0 = fmaf(u0[2], o2, pp0); pp0 = fmaf(u0[3], o3, pp0);
      float pp1 = u1[0] * o0;
      pp1 = fmaf(u1[1], o1, pp1); pp1 = fmaf(u1[2], o2, pp1); pp1 = fmaf(u1[3], o3, pp1);
      pp0 += __shfl_xor(pp0, 16); pp0 += __shfl_xor(pp0, 32);   // full dot; replicated over g
      pp1 += __shfl_xor(pp1, 16); pp1 += __shfl_xor(pp1, 32);
      p4[0][k & 3] = pp0;
      p4[1][k & 3] = pp1;
      if ((k & 3) == 3) {
        // g-group g stores k' = (k&~3)+g (static selects; full-wave 4x64B store)
#pragma unroll
        for (int jc = 0; jc < JCA; ++jc) {
          float val = p4[jc][0];
          val = (g == 1) ? p4[jc][1] : val;
          val = (g == 2) ? p4[jc][2] : val;
          val = (g == 3) ? p4[jc][3] : val;
          pT[((size_t)(jb * JCA + jc) * 32 + (k & ~3) + g) * 64 + b] = val;
        }
      }
    }
  }
}

// ---------------- k_soft: softmax over k, cT[j][k][b] in-place. Block = 4 j (1 wave each).
// All loads/stores wave-coalesced (256B per k); reduction purely in-thread.
__global__ __launch_bounds__(256) void k_soft(float* __restrict__ cT) {
  const int j = blockIdx.x * 4 + (threadIdx.x >> 6);
  const int b = threadIdx.x & 63;
  float* base = cT + (size_t)j * 2048 + b;    // + k*64
  float v[32];
  float S = 0.f;
#pragma unroll
  for (int k = 0; k < 32; ++k) {
    // logits O(+-4): skip max-subtraction (softmax shift-invariant; validated r1-r8)
    v[k] = __expf(base[(size_t)k * 64]);
    S += v[k];
  }
  const float rS = __builtin_amdgcn_rcpf(S);
#pragma unroll
  for (int k = 0; k < 32; ++k) base[(size_t)k * 64] = v[k] * rS;
}

// ---------------- k_cout: cT[j][k][b] -> outp[b][k][16+j], block = (k, j-chunk of 128).
__global__ __launch_bounds__(256) void k_cout(const float* __restrict__ cT,
                                              float* __restrict__ outp) {
  const int k = blockIdx.x & 31, j0 = (blockIdx.x >> 5) * 128;
  const int t = threadIdx.x;
  __shared__ float lds[64][129];
#pragma unroll
  for (int m = 0; m < 32; ++m) {
    const int jj = m * 4 + (t >> 6), b = t & 63;
    lds[b][jj] = cT[((size_t)(j0 + jj) * 32 + k) * 64 + b];   // coalesced 256B
  }
  __syncthreads();
#pragma unroll
  for (int m = 0; m < 8; ++m) {
    const int b = m * 8 + (t >> 5), jq = (t & 31) * 4;
    *(float4*)(outp + ((size_t)b * 32 + k) * 2064 + 16 + j0 + jq) =
        make_float4(lds[b][jq], lds[b][jq + 1], lds[b][jq + 2], lds[b][jq + 3]);
  }
}

// ---------------- k_B: s[b][kd] partials via MFMA, c folded into B-frag.
// All 48 loads hoisted into one latency window (128-VGPR budget); j-pairs in slots 4-7.
template <int CMODE>
__global__ __launch_bounds__(256, 4) void k_B(const unsigned short* __restrict__ XT,
                                              const unsigned short* __restrict__ WB,
                                              const float* __restrict__ cT,
                                              float* __restrict__ spart) {
  const int x = blockIdx.x;
  const int ch = x >> 5, k = x & 31;
  const int t = threadIdx.x;
  const int wave = t >> 6, lane = t & 63;
  const int g = lane >> 4, r = lane & 15;
  const int b = wave * 16 + r;
  const int j0 = ch * JCB;

  const unsigned short* wp = WB + ((size_t)j0 * 32 + k) * 256 + r * 16 + 4 * g;
  const unsigned short* xp = XT + ((size_t)j0 * 64 + b) * 16 + 4 * g;
  const float* cp = cT + ((size_t)j0 * 32 + k) * 64 + b;

  // ---- hoist ALL loads: 48 independent VMEM ops in flight together
  uint2 wv[JCB], xv[JCB];
  float cv[JCB];
#pragma unroll
  for (int jc = 0; jc < JCB; ++jc) wv[jc] = *(const uint2*)(wp + (size_t)jc * 8192);
#pragma unroll
  for (int jc = 0; jc < JCB; ++jc) xv[jc] = *(const uint2*)(xp + (size_t)jc * 1024);
  if constexpr (CMODE == 1) {
#pragma unroll
    for (int jc = 0; jc < JCB; ++jc) cv[jc] = cp[(size_t)jc * 2048];   // 1 x 64B line/wave
  }

  // ---- compute: 8 j-pair MFMAs (slots 0-3 = even j, 4-7 = odd j; same map A and B)
  f32x4 acc = {0.f, 0.f, 0.f, 0.f};
#pragma unroll
  for (int jp = 0; jp < 8; ++jp) {
    const int ja = 2 * jp, jb2 = 2 * jp + 1;
    const short8v af = mk_frag4(wv[ja].x, wv[ja].y, wv[jb2].x, wv[jb2].y);
    short8v bf;
    if constexpr (CMODE == 1) {
      const float ca = cv[ja], cb = cv[jb2];
      const unsigned int p0 = f2bf(bf2f(xv[ja].x & 0xffffu) * ca) |
                              (f2bf(bf2f(xv[ja].x >> 16) * ca) << 16);
      const unsigned int p1 = f2bf(bf2f(xv[ja].y & 0xffffu) * ca) |
                              (f2bf(bf2f(xv[ja].y >> 16) * ca) << 16);
      const unsigned int p2 = f2bf(bf2f(xv[jb2].x & 0xffffu) * cb) |
                              (f2bf(bf2f(xv[jb2].x >> 16) * cb) << 16);
      const unsigned int p3 = f2bf(bf2f(xv[jb2].y & 0xffffu) * cb) |
                              (f2bf(bf2f(xv[jb2].y >> 16) * cb) << 16);
      bf = mk_frag4(p0, p1, p2, p3);
    } else {
      bf = mk_frag4(xv[ja].x, xv[ja].y, xv[jb2].x, xv[jb2].y);
    }
    acc = __builtin_amdgcn_mfma_f32_16x16x32_bf16(af, bf, acc, 0, 0, 0);
  }
  const float sc = (CMODE == 0) ? (1.f / 32.f) : 1.f;
  // C layout: col = b (lane&15), row = d = 4g + reg  ->  16B contiguous store
  *(float4*)(spart + (((size_t)b * CHB + ch) * 32 + k) * 16 + 4 * g) =
      make_float4(acc[0] * sc, acc[1] * sc, acc[2] * sc, acc[3] * sc);
}

// ---------------- squash: reduce spart -> s, squash -> o; f32 osum + bf16 [k][b][d] mirror.
__global__ __launch_bounds__(256) void k_squash(const float* __restrict__ spart,
                                                float* __restrict__ osum,
                                                unsigned short* __restrict__ osum_bf,
                                                float* __restrict__ outp,
                                                int first, int final_) {
  const int t = threadIdx.x;
  const int wave = t >> 6, lane = t & 63;
  const int gw = blockIdx.x * 4 + wave;   // 0..B_*K_-1
  const int b = gw >> 5, k = gw & 31;
  const int d = lane & 15, pg = lane >> 4;
  float s = 0.f;
  for (int p = pg; p < CHB; p += 4)
    s += spart[(((size_t)b * CHB + p) * 32 + k) * 16 + d];
  s += __shfl_xor(s, 16);
  s += __shfl_xor(s, 32);
  float ss = s * s;
  ss += __shfl_xor(ss, 1); ss += __shfl_xor(ss, 2);
  ss += __shfl_xor(ss, 4); ss += __shfl_xor(ss, 8);
  const float scale = (ss / (1.f + ss)) * rsqrtf(ss + 1e-7f);
  const float ov = scale * s;
  if (final_) {
    if (lane < 16) outp[((size_t)b * K_ + k) * 2064 + d] = ov;
  } else {
    const float prev = first ? 0.f : osum[b * KD + k * 16 + d];
    const float ns = prev + ov;
    const float partner = __shfl_xor(ns, 1);
    if (lane < 16) {
      osum[b * KD + k * 16 + d] = ns;
      if (!(lane & 1)) {
        const unsigned int pk = f2bf(ns) | (f2bf(partner) << 16);
        *(unsigned int*)(osum_bf + ((size_t)k * 64 + b) * 16 + d) = pk;
      }
    }
  }
}

extern "C" void kernel_launch(void* const* d_in, const int* in_sizes, int n_in,
                              void* d_out, int out_size, void* d_ws, size_t ws_size,
                              hipStream_t stream) {
  const float* inp = (const float*)d_in[0];   // [64,2048,16]
  const float* W   = (const float*)d_in[1];   // [32,2048,16,16]
  float* outp = (float*)d_out;                // [64,32,2064]
  char* ws = (char*)d_ws;
  // ws: WB 32M | XT 4M | cT 16M | spart 16M | osum 128K | osum_bf 64K  (~68.2 MiB)
  unsigned short* WB = (unsigned short*)ws;
  unsigned short* XT = (unsigned short*)(ws + (size_t)33554432);
  float* cT    = (float*)(ws + (size_t)33554432 + 4194304);
  float* spart = (float*)(ws + (size_t)33554432 + 4194304 + 16777216);
  float* osum  = (float*)(ws + (size_t)33554432 + 4194304 + 16777216 + 16777216);
  unsigned short* osum_bf =
      (unsigned short*)(ws + (size_t)33554432 + 4194304 + 16777216 + 16777216 + 131072);

  k_prep<<<2048, 256, 0, stream>>>(inp, W, WB, XT);
  // iter 0: c = 1/32
  k_B<0><<<CHB * K_, 256, 0, stream>>>(XT, WB, nullptr, spart);
  k_squash<<<B_ * K_ / 4, 256, 0, stream>>>(spart, osum, osum_bf, outp, 1, 0);
  // iter 1
  k_A<<<J_ / JCA, 256, 0, stream>>>(XT, WB, osum_bf, cT);
  k_soft<<<J_ / 4, 256, 0, stream>>>(cT);
  k_B<1><<<CHB * K_, 256, 0, stream>>>(XT, WB, cT, spart);
  k_squash<<<B_ * K_ / 4, 256, 0, stream>>>(spart, osum, osum_bf, outp, 0, 0);
  // iter 2 (final)
  k_A<<<J_ / JCA, 256, 0, stream>>>(XT, WB, osum_bf, cT);
  k_soft<<<J_ / 4, 256, 0, stream>>>(cT);
  k_cout<<<K_ * 16, 256, 0, stream>>>(cT, outp);
  k_B<1><<<CHB * K_, 256, 0, stream>>>(XT, WB, cT, spart);
  k_squash<<<B_ * K_ / 4, 256, 0, stream>>>(spart, osum, osum_bf, outp, 0, 1);
}

// Round 10
// 144.212 us; speedup vs baseline: 1.7674x; 1.3767x over previous
//
#include <hip/hip_runtime.h>
#include <hip/hip_bf16.h>

#define B_ 64
#define J_ 2048
#define K_ 32
#define D_ 16
#define KD 512
#define CHB 128      // k_B j-chunks (spart partials)
#define JCB 16       // j's per k_B chunk

typedef __attribute__((ext_vector_type(8))) short short8v;    // 8 bf16 (4 VGPR)
typedef __attribute__((ext_vector_type(4))) float f32x4;      // 4 f32 acc
typedef __attribute__((ext_vector_type(16))) float f32x16;    // 16 f32 acc (32x32)

__device__ __forceinline__ float bf2f(unsigned int bits16) {
  unsigned int u = bits16 << 16;
  return __builtin_bit_cast(float, u);
}
__device__ __forceinline__ unsigned int f2bf(float f) {
  unsigned int u = __builtin_bit_cast(unsigned int, f);
  u = u + 0x7fffu + ((u >> 16) & 1u);   // round-to-nearest-even
  return u >> 16;
}
__device__ __forceinline__ short8v mk_frag(unsigned int d0, unsigned int d1) {
  uint4 t = make_uint4(d0, d1, 0u, 0u);        // k-slots 4..7 zero
  return __builtin_bit_cast(short8v, t);
}
__device__ __forceinline__ short8v mk_frag4(unsigned int d0, unsigned int d1,
                                            unsigned int d2, unsigned int d3) {
  uint4 t = make_uint4(d0, d1, d2, d3);        // slots 0-3 = j0, 4-7 = j1
  return __builtin_bit_cast(short8v, t);
}
__device__ __forceinline__ f32x16 zero16() {
  f32x16 z;
#pragma unroll
  for (int i = 0; i < 16; ++i) z[i] = 0.f;
  return z;
}

// ---------------- prep: WB[j][k][d][i] = bf16(W[k][j][d][i]);  XT[j][b][i] = bf16(x[b][j][i])
__global__ __launch_bounds__(256) void k_prep(const float* __restrict__ inp,
                                              const float* __restrict__ W,
                                              unsigned short* __restrict__ WB,
                                              unsigned short* __restrict__ XT) {
  const size_t tid = (size_t)blockIdx.x * 256 + threadIdx.x;
  const size_t stride = (size_t)gridDim.x * 256;
  for (size_t g8 = tid; g8 < (size_t)J_ * K_ * 32; g8 += stride) {
    const size_t o = g8 * 8;
    const int j = (int)(o >> 13), k = (int)((o >> 8) & 31), di = (int)(o & 255);
    const float* src = W + ((size_t)k * J_ + j) * 256 + di;
    const float4 a = *(const float4*)src;
    const float4 b = *(const float4*)(src + 4);
    uint4 pk;
    pk.x = f2bf(a.x) | (f2bf(a.y) << 16);
    pk.y = f2bf(a.z) | (f2bf(a.w) << 16);
    pk.z = f2bf(b.x) | (f2bf(b.y) << 16);
    pk.w = f2bf(b.z) | (f2bf(b.w) << 16);
    *(uint4*)(WB + o) = pk;
  }
  for (size_t g8 = tid; g8 < (size_t)J_ * B_ * 2; g8 += stride) {
    const size_t o = g8 * 8;
    const int j = (int)(o >> 10), b = (int)((o >> 4) & 63), i0 = (int)(o & 15);
    const float* src = inp + ((size_t)b * J_ + j) * 16 + i0;
    const float4 a = *(const float4*)src;
    const float4 c = *(const float4*)(src + 4);
    uint4 pk;
    pk.x = f2bf(a.x) | (f2bf(a.y) << 16);
    pk.y = f2bf(a.z) | (f2bf(a.w) << 16);
    pk.z = f2bf(c.x) | (f2bf(c.y) << 16);
    pk.w = f2bf(c.z) | (f2bf(c.w) << 16);
    *(uint4*)(XT + o) = pk;
  }
}

// ---------------- k_A (32x32 MFMA): c[j][k][b] = softmax_k(osum . u_hat) directly.
// Block = 2 j's x 4 waves; wave = (jc = w>>1, b-tile bt = w&1). Per wave: 16 MFMAs
// (A = W[j] 32 kd-rows x 16 i, B = x^T 32 b). Lane (hi,b31) gets u for 2 k's x 8 d's
// -> 8-fma dot with osB + ONE shfl_xor(32) -> full logit in-lane -> in-register
// softmax over 32 k (e packed bf16), direct c store. No k_soft pass needed.
// osB layout (from k_squash): [k][bt][lane=hi*32+b31][slot0-7], slot->d = (s&3)+4hi+8*(s>>2).
__global__ __launch_bounds__(256, 4) void k_A(const unsigned short* __restrict__ XT,
                                              const unsigned short* __restrict__ WB,
                                              const unsigned short* __restrict__ osB,
                                              float* __restrict__ cT) {
  const int jb = blockIdx.x;
  const int t = threadIdx.x;
  const int wave = t >> 6, lane = t & 63;
  const int jc = wave >> 1, bt = wave & 1;
  const int j = jb * 2 + jc;
  const int hi = lane >> 5, b31 = lane & 31;
  const int b = bt * 32 + b31;

  // B-frag: x[j][b][i], slots = i in [8hi, 8hi+8)
  const short8v xf = __builtin_bit_cast(short8v,
      *(const uint4*)(XT + (size_t)j * 1024 + b * 16 + 8 * hi));

  // A-frag base: lane's A-row = b31 -> k-parity = b31>>4, d = b31&15; + kpair*512
  const unsigned short* wa =
      WB + (size_t)j * 8192 + (b31 >> 4) * 256 + (b31 & 15) * 16 + 8 * hi;
  // osB base: + k*1024
  const unsigned short* osb = osB + ((size_t)bt * 64 + lane) * 8;

  float S = 0.f;
  unsigned int e_pk[16];                       // bf16-packed e for k = 2tp, 2tp+1

#pragma unroll
  for (int grp = 0; grp < 4; ++grp) {
    // batch-issue loads for 4 k-pairs
    uint4 av[4], os0[4], os1[4];
#pragma unroll
    for (int q = 0; q < 4; ++q) {
      const int tp = grp * 4 + q;
      av[q]  = *(const uint4*)(wa + (size_t)tp * 512);
      os0[q] = *(const uint4*)(osb + (size_t)(2 * tp) * 1024);
      os1[q] = *(const uint4*)(osb + (size_t)(2 * tp + 1) * 1024);
    }
#pragma unroll
    for (int q = 0; q < 4; ++q) {
      const int tp = grp * 4 + q;
      const f32x16 u = __builtin_amdgcn_mfma_f32_32x32x16_bf16(
          __builtin_bit_cast(short8v, av[q]), xf, zero16(), 0, 0, 0);
      const unsigned int* o0 = (const unsigned int*)&os0[q];
      const unsigned int* o1 = (const unsigned int*)&os1[q];
      float pe = 0.f, po = 0.f;
#pragma unroll
      for (int s = 0; s < 8; ++s) {
        const unsigned int w0 = o0[s >> 1], w1 = o1[s >> 1];
        const float f0 = bf2f((s & 1) ? (w0 >> 16) : (w0 & 0xffffu));
        const float f1 = bf2f((s & 1) ? (w1 >> 16) : (w1 & 0xffffu));
        pe = fmaf(u[s], f0, pe);         // regs 0-7: k even, d = (s&3)+4hi+8*(s>>2)
        po = fmaf(u[8 + s], f1, po);     // regs 8-15: k odd, same d order
      }
      pe += __shfl_xor(pe, 32);          // add partner hi-half: full dot over d
      po += __shfl_xor(po, 32);
      // logits O(+-8): skip max-subtraction (shift-invariant; validated r1-r9)
      const float ee = __expf(pe), eo = __expf(po);
      S += ee + eo;
      e_pk[tp] = f2bf(ee) | (f2bf(eo) << 16);
    }
  }

  const float rS = __builtin_amdgcn_rcpf(S);
  if (hi == 0) {                         // lanes 0-31: b-contiguous 128B stores
    float* cp = cT + (size_t)j * 2048 + b;        // + k*64
#pragma unroll
    for (int tp = 0; tp < 16; ++tp) {
      cp[(size_t)(2 * tp) * 64]     = bf2f(e_pk[tp] & 0xffffu) * rS;
      cp[(size_t)(2 * tp + 1) * 64] = bf2f(e_pk[tp] >> 16) * rS;
    }
  }
}

// ---------------- k_cout: cT[j][k][b] -> outp[b][k][16+j], block = (k, j-chunk of 128).
__global__ __launch_bounds__(256) void k_cout(const float* __restrict__ cT,
                                              float* __restrict__ outp) {
  const int k = blockIdx.x & 31, j0 = (blockIdx.x >> 5) * 128;
  const int t = threadIdx.x;
  __shared__ float lds[64][129];
#pragma unroll
  for (int m = 0; m < 32; ++m) {
    const int jj = m * 4 + (t >> 6), b = t & 63;
    lds[b][jj] = cT[((size_t)(j0 + jj) * 32 + k) * 64 + b];   // coalesced 256B
  }
  __syncthreads();
#pragma unroll
  for (int m = 0; m < 8; ++m) {
    const int b = m * 8 + (t >> 5), jq = (t & 31) * 4;
    *(float4*)(outp + ((size_t)b * 32 + k) * 2064 + 16 + j0 + jq) =
        make_float4(lds[b][jq], lds[b][jq + 1], lds[b][jq + 2], lds[b][jq + 3]);
  }
}

// ---------------- k_B: s[b][kd] partials via MFMA, c folded into B-frag.
// All 48 loads hoisted into one latency window (128-VGPR budget); j-pairs in slots 4-7.
template <int CMODE>
__global__ __launch_bounds__(256, 4) void k_B(const unsigned short* __restrict__ XT,
                                              const unsigned short* __restrict__ WB,
                                              const float* __restrict__ cT,
                                              float* __restrict__ spart) {
  const int x = blockIdx.x;
  const int ch = x >> 5, k = x & 31;
  const int t = threadIdx.x;
  const int wave = t >> 6, lane = t & 63;
  const int g = lane >> 4, r = lane & 15;
  const int b = wave * 16 + r;
  const int j0 = ch * JCB;

  const unsigned short* wp = WB + ((size_t)j0 * 32 + k) * 256 + r * 16 + 4 * g;
  const unsigned short* xp = XT + ((size_t)j0 * 64 + b) * 16 + 4 * g;
  const float* cp = cT + ((size_t)j0 * 32 + k) * 64 + b;

  // ---- hoist ALL loads: 48 independent VMEM ops in flight together
  uint2 wv[JCB], xv[JCB];
  float cv[JCB];
#pragma unroll
  for (int jc = 0; jc < JCB; ++jc) wv[jc] = *(const uint2*)(wp + (size_t)jc * 8192);
#pragma unroll
  for (int jc = 0; jc < JCB; ++jc) xv[jc] = *(const uint2*)(xp + (size_t)jc * 1024);
  if constexpr (CMODE == 1) {
#pragma unroll
    for (int jc = 0; jc < JCB; ++jc) cv[jc] = cp[(size_t)jc * 2048];   // 1 x 64B line/wave
  }

  // ---- compute: 8 j-pair MFMAs (slots 0-3 = even j, 4-7 = odd j; same map A and B)
  f32x4 acc = {0.f, 0.f, 0.f, 0.f};
#pragma unroll
  for (int jp = 0; jp < 8; ++jp) {
    const int ja = 2 * jp, jb2 = 2 * jp + 1;
    const short8v af = mk_frag4(wv[ja].x, wv[ja].y, wv[jb2].x, wv[jb2].y);
    short8v bf;
    if constexpr (CMODE == 1) {
      const float ca = cv[ja], cb = cv[jb2];
      const unsigned int p0 = f2bf(bf2f(xv[ja].x & 0xffffu) * ca) |
                              (f2bf(bf2f(xv[ja].x >> 16) * ca) << 16);
      const unsigned int p1 = f2bf(bf2f(xv[ja].y & 0xffffu) * ca) |
                              (f2bf(bf2f(xv[ja].y >> 16) * ca) << 16);
      const unsigned int p2 = f2bf(bf2f(xv[jb2].x & 0xffffu) * cb) |
                              (f2bf(bf2f(xv[jb2].x >> 16) * cb) << 16);
      const unsigned int p3 = f2bf(bf2f(xv[jb2].y & 0xffffu) * cb) |
                              (f2bf(bf2f(xv[jb2].y >> 16) * cb) << 16);
      bf = mk_frag4(p0, p1, p2, p3);
    } else {
      bf = mk_frag4(xv[ja].x, xv[ja].y, xv[jb2].x, xv[jb2].y);
    }
    acc = __builtin_amdgcn_mfma_f32_16x16x32_bf16(af, bf, acc, 0, 0, 0);
  }
  const float sc = (CMODE == 0) ? (1.f / 32.f) : 1.f;
  // C layout: col = b (lane&15), row = d = 4g + reg  ->  16B contiguous store
  *(float4*)(spart + (((size_t)b * CHB + ch) * 32 + k) * 16 + 4 * g) =
      make_float4(acc[0] * sc, acc[1] * sc, acc[2] * sc, acc[3] * sc);
}

// ---------------- squash: reduce spart -> s, squash -> o; f32 osum master +
// bf16 osB mirror in k_A's fragment layout [k][bt][hi*32+b31][slot].
__global__ __launch_bounds__(256) void k_squash(const float* __restrict__ spart,
                                                float* __restrict__ osum,
                                                unsigned short* __restrict__ osB,
                                                float* __restrict__ outp,
                                                int first, int final_) {
  const int t = threadIdx.x;
  const int wave = t >> 6, lane = t & 63;
  const int gw = blockIdx.x * 4 + wave;   // 0..B_*K_-1
  const int b = gw >> 5, k = gw & 31;
  const int d = lane & 15, pg = lane >> 4;
  float s = 0.f;
  for (int p = pg; p < CHB; p += 4)
    s += spart[(((size_t)b * CHB + p) * 32 + k) * 16 + d];
  s += __shfl_xor(s, 16);
  s += __shfl_xor(s, 32);
  float ss = s * s;
  ss += __shfl_xor(ss, 1); ss += __shfl_xor(ss, 2);
  ss += __shfl_xor(ss, 4); ss += __shfl_xor(ss, 8);
  const float scale = (ss / (1.f + ss)) * rsqrtf(ss + 1e-7f);
  const float ov = scale * s;
  if (final_) {
    if (lane < 16) outp[((size_t)b * K_ + k) * 2064 + d] = ov;
  } else {
    const float prev = first ? 0.f : osum[b * KD + k * 16 + d];
    const float ns = prev + ov;
    if (lane < 16) {
      osum[b * KD + k * 16 + d] = ns;
      // osB scatter: d -> (hi, slot): hi = (d>>2)&1, slot = (d&3) + 4*(d>>3)
      const int hi = (d >> 2) & 1;
      const int slot = (d & 3) + ((d >> 3) << 2);
      osB[(((size_t)k * 2 + (b >> 5)) * 64 + hi * 32 + (b & 31)) * 8 + slot] = f2bf(ns);
    }
  }
}

extern "C" void kernel_launch(void* const* d_in, const int* in_sizes, int n_in,
                              void* d_out, int out_size, void* d_ws, size_t ws_size,
                              hipStream_t stream) {
  const float* inp = (const float*)d_in[0];   // [64,2048,16]
  const float* W   = (const float*)d_in[1];   // [32,2048,16,16]
  float* outp = (float*)d_out;                // [64,32,2064]
  char* ws = (char*)d_ws;
  // ws: WB 32M | XT 4M | cT 16M | spart 16M | osum 128K | osB 64K  (~68.2 MiB)
  unsigned short* WB = (unsigned short*)ws;
  unsigned short* XT = (unsigned short*)(ws + (size_t)33554432);
  float* cT    = (float*)(ws + (size_t)33554432 + 4194304);
  float* spart = (float*)(ws + (size_t)33554432 + 4194304 + 16777216);
  float* osum  = (float*)(ws + (size_t)33554432 + 4194304 + 16777216 + 16777216);
  unsigned short* osB =
      (unsigned short*)(ws + (size_t)33554432 + 4194304 + 16777216 + 16777216 + 131072);

  k_prep<<<2048, 256, 0, stream>>>(inp, W, WB, XT);
  // iter 0: c = 1/32
  k_B<0><<<CHB * K_, 256, 0, stream>>>(XT, WB, nullptr, spart);
  k_squash<<<B_ * K_ / 4, 256, 0, stream>>>(spart, osum, osB, outp, 1, 0);
  // iter 1
  k_A<<<J_ / 2, 256, 0, stream>>>(XT, WB, osB, cT);
  k_B<1><<<CHB * K_, 256, 0, stream>>>(XT, WB, cT, spart);
  k_squash<<<B_ * K_ / 4, 256, 0, stream>>>(spart, osum, osB, outp, 0, 0);
  // iter 2 (final)
  k_A<<<J_ / 2, 256, 0, stream>>>(XT, WB, osB, cT);
  k_cout<<<K_ * 16, 256, 0, stream>>>(cT, outp);
  k_B<1><<<CHB * K_, 256, 0, stream>>>(XT, WB, cT, spart);
  k_squash<<<B_ * K_ / 4, 256, 0, stream>>>(spart, osum, osB, outp, 0, 1);
}

// Round 11
// 125.258 us; speedup vs baseline: 2.0348x; 1.1513x over previous
//
#include <hip/hip_runtime.h>
#include <hip/hip_bf16.h>

#define B_ 64
#define J_ 2048
#define K_ 32
#define D_ 16
#define KD 512
#define CHB 32       // k_B j-chunks (spart partials)
#define JCB 64       // j's per k_B chunk

typedef __attribute__((ext_vector_type(8))) short short8v;    // 8 bf16 (4 VGPR)
typedef __attribute__((ext_vector_type(4))) float f32x4;      // 4 f32 acc
typedef __attribute__((ext_vector_type(16))) float f32x16;    // 16 f32 acc (32x32)

__device__ __forceinline__ float bf2f(unsigned int bits16) {
  unsigned int u = bits16 << 16;
  return __builtin_bit_cast(float, u);
}
__device__ __forceinline__ unsigned int f2bf(float f) {
  unsigned int u = __builtin_bit_cast(unsigned int, f);
  u = u + 0x7fffu + ((u >> 16) & 1u);   // round-to-nearest-even
  return u >> 16;
}
__device__ __forceinline__ short8v mk_frag4(unsigned int d0, unsigned int d1,
                                            unsigned int d2, unsigned int d3) {
  uint4 t = make_uint4(d0, d1, d2, d3);        // slots 0-3 = j0, 4-7 = j1
  return __builtin_bit_cast(short8v, t);
}
__device__ __forceinline__ f32x16 zero16() {
  f32x16 z;
#pragma unroll
  for (int i = 0; i < 16; ++i) z[i] = 0.f;
  return z;
}

// ---------------- prep: WB[j][k][d][i] = bf16(W[k][j][d][i]);  XT[j][b][i] = bf16(x[b][j][i])
__global__ __launch_bounds__(256) void k_prep(const float* __restrict__ inp,
                                              const float* __restrict__ W,
                                              unsigned short* __restrict__ WB,
                                              unsigned short* __restrict__ XT) {
  const size_t tid = (size_t)blockIdx.x * 256 + threadIdx.x;
  const size_t stride = (size_t)gridDim.x * 256;
  for (size_t g8 = tid; g8 < (size_t)J_ * K_ * 32; g8 += stride) {
    const size_t o = g8 * 8;
    const int j = (int)(o >> 13), k = (int)((o >> 8) & 31), di = (int)(o & 255);
    const float* src = W + ((size_t)k * J_ + j) * 256 + di;
    const float4 a = *(const float4*)src;
    const float4 b = *(const float4*)(src + 4);
    uint4 pk;
    pk.x = f2bf(a.x) | (f2bf(a.y) << 16);
    pk.y = f2bf(a.z) | (f2bf(a.w) << 16);
    pk.z = f2bf(b.x) | (f2bf(b.y) << 16);
    pk.w = f2bf(b.z) | (f2bf(b.w) << 16);
    *(uint4*)(WB + o) = pk;
  }
  for (size_t g8 = tid; g8 < (size_t)J_ * B_ * 2; g8 += stride) {
    const size_t o = g8 * 8;
    const int j = (int)(o >> 10), b = (int)((o >> 4) & 63), i0 = (int)(o & 15);
    const float* src = inp + ((size_t)b * J_ + j) * 16 + i0;
    const float4 a = *(const float4*)src;
    const float4 c = *(const float4*)(src + 4);
    uint4 pk;
    pk.x = f2bf(a.x) | (f2bf(a.y) << 16);
    pk.y = f2bf(a.z) | (f2bf(a.w) << 16);
    pk.z = f2bf(c.x) | (f2bf(c.y) << 16);
    pk.w = f2bf(c.z) | (f2bf(c.w) << 16);
    *(uint4*)(XT + o) = pk;
  }
}

// ---------------- k_A (32x32 MFMA): c[j][k][b] = softmax_k(osum . u_hat) directly.
// Block = 4 j's, grid 512 (2 blocks/CU). Wave = (jg = w>>1, bt = w&1) handles j's
// {jb*4+jg*2, +1} for b-tile bt: os loaded + decoded ONCE per k-pair, reused by both j.
// Lane (hi,b31): u for 2 k's x 8 d's -> 8-fma dot + one shfl_xor(32) -> in-register
// softmax over 32 k, direct c store. osB layout [k][bt][lane][slot] as r10 (validated).
__global__ __launch_bounds__(256, 2) void k_A(const unsigned short* __restrict__ XT,
                                              const unsigned short* __restrict__ WB,
                                              const unsigned short* __restrict__ osB,
                                              float* __restrict__ cT) {
  const int jb = blockIdx.x;
  const int t = threadIdx.x;
  const int wave = t >> 6, lane = t & 63;
  const int jg = wave >> 1, bt = wave & 1;
  const int jB = jb * 4 + jg * 2;              // wave's j's: jB, jB+1
  const int hi = lane >> 5, b31 = lane & 31;
  const int b = bt * 32 + b31;

  // B-frags: x[j][b][i], slots = i in [8hi, 8hi+8)
  short8v xf[2];
#pragma unroll
  for (int jj = 0; jj < 2; ++jj)
    xf[jj] = __builtin_bit_cast(short8v,
        *(const uint4*)(XT + (size_t)(jB + jj) * 1024 + b * 16 + 8 * hi));

  // A-frag bases: lane's A-row = b31 -> k-parity = b31>>4, d = b31&15; + kpair*512
  const unsigned short* wa0 =
      WB + (size_t)jB * 8192 + (b31 >> 4) * 256 + (b31 & 15) * 16 + 8 * hi;
  const unsigned short* osb = osB + ((size_t)bt * 64 + lane) * 8;   // + k*1024

  float S[2] = {0.f, 0.f};
  unsigned int e_pk[2][16];                    // bf16-packed e for k = 2tp, 2tp+1

#pragma unroll
  for (int grp = 0; grp < 4; ++grp) {
    // batch-issue loads for 4 k-pairs (os shared across both j)
    uint4 os0[4], os1[4], av[2][4];
#pragma unroll
    for (int q = 0; q < 4; ++q) {
      const int tp = grp * 4 + q;
      os0[q] = *(const uint4*)(osb + (size_t)(2 * tp) * 1024);
      os1[q] = *(const uint4*)(osb + (size_t)(2 * tp + 1) * 1024);
      av[0][q] = *(const uint4*)(wa0 + (size_t)tp * 512);
      av[1][q] = *(const uint4*)(wa0 + 8192 + (size_t)tp * 512);
    }
#pragma unroll
    for (int q = 0; q < 4; ++q) {
      const int tp = grp * 4 + q;
      // decode os once, reuse for both j
      const unsigned int* o0 = (const unsigned int*)&os0[q];
      const unsigned int* o1 = (const unsigned int*)&os1[q];
      float f0v[8], f1v[8];
#pragma unroll
      for (int s = 0; s < 8; ++s) {
        const unsigned int w0 = o0[s >> 1], w1 = o1[s >> 1];
        f0v[s] = bf2f((s & 1) ? (w0 >> 16) : (w0 & 0xffffu));
        f1v[s] = bf2f((s & 1) ? (w1 >> 16) : (w1 & 0xffffu));
      }
#pragma unroll
      for (int jj = 0; jj < 2; ++jj) {
        const f32x16 u = __builtin_amdgcn_mfma_f32_32x32x16_bf16(
            __builtin_bit_cast(short8v, av[jj][q]), xf[jj], zero16(), 0, 0, 0);
        float pe = 0.f, po = 0.f;
#pragma unroll
        for (int s = 0; s < 8; ++s) {
          pe = fmaf(u[s], f0v[s], pe);       // regs 0-7: k even, d=(s&3)+4hi+8*(s>>2)
          po = fmaf(u[8 + s], f1v[s], po);   // regs 8-15: k odd
        }
        pe += __shfl_xor(pe, 32);            // partner hi-half: full dot over d
        po += __shfl_xor(po, 32);
        // logits O(+-8): skip max-subtraction (shift-invariant; validated r1-r10)
        const float ee = __expf(pe), eo = __expf(po);
        S[jj] += ee + eo;
        e_pk[jj][tp] = f2bf(ee) | (f2bf(eo) << 16);
      }
    }
  }

  if (hi == 0) {                             // lanes 0-31: b-contiguous 128B stores
#pragma unroll
    for (int jj = 0; jj < 2; ++jj) {
      const float rS = __builtin_amdgcn_rcpf(S[jj]);
      float* cp = cT + (size_t)(jB + jj) * 2048 + b;      // + k*64
#pragma unroll
      for (int tp = 0; tp < 16; ++tp) {
        cp[(size_t)(2 * tp) * 64]     = bf2f(e_pk[jj][tp] & 0xffffu) * rS;
        cp[(size_t)(2 * tp + 1) * 64] = bf2f(e_pk[jj][tp] >> 16) * rS;
      }
    }
  }
}

// ---------------- k_cout: cT[j][k][b] -> outp[b][k][16+j], block = (k, j-chunk of 128).
__global__ __launch_bounds__(256) void k_cout(const float* __restrict__ cT,
                                              float* __restrict__ outp) {
  const int k = blockIdx.x & 31, j0 = (blockIdx.x >> 5) * 128;
  const int t = threadIdx.x;
  __shared__ float lds[64][129];
#pragma unroll
  for (int m = 0; m < 32; ++m) {
    const int jj = m * 4 + (t >> 6), b = t & 63;
    lds[b][jj] = cT[((size_t)(j0 + jj) * 32 + k) * 64 + b];   // coalesced 256B
  }
  __syncthreads();
#pragma unroll
  for (int m = 0; m < 8; ++m) {
    const int b = m * 8 + (t >> 5), jq = (t & 31) * 4;
    *(float4*)(outp + ((size_t)b * 32 + k) * 2064 + 16 + j0 + jq) =
        make_float4(lds[b][jq], lds[b][jq + 1], lds[b][jq + 2], lds[b][jq + 3]);
  }
}

// ---------------- k_B: s[b][kd] partials via MFMA, c folded into B-frag.
// Grid 1024 (= 4 blocks/CU co-resident). Block = (ch, k), 64 j's in 4 batches of 16;
// each batch = one 48-load window; acc chains across batches (K-loop accumulator).
template <int CMODE>
__global__ __launch_bounds__(256, 4) void k_B(const unsigned short* __restrict__ XT,
                                              const unsigned short* __restrict__ WB,
                                              const float* __restrict__ cT,
                                              float* __restrict__ spart) {
  const int x = blockIdx.x;
  const int ch = x >> 5, k = x & 31;
  const int t = threadIdx.x;
  const int wave = t >> 6, lane = t & 63;
  const int g = lane >> 4, r = lane & 15;
  const int b = wave * 16 + r;
  const int j0 = ch * JCB;

  const unsigned short* wp = WB + ((size_t)j0 * 32 + k) * 256 + r * 16 + 4 * g;
  const unsigned short* xp = XT + ((size_t)j0 * 64 + b) * 16 + 4 * g;
  const float* cp = cT + ((size_t)j0 * 32 + k) * 64 + b;

  f32x4 acc = {0.f, 0.f, 0.f, 0.f};
#pragma unroll
  for (int batch = 0; batch < 4; ++batch) {
    const int jb0 = batch * 16;
    // ---- hoist one batch: 48 independent VMEM ops in flight
    uint2 wv[16], xv[16];
    float cv[16];
#pragma unroll
    for (int jc = 0; jc < 16; ++jc)
      wv[jc] = *(const uint2*)(wp + (size_t)(jb0 + jc) * 8192);
#pragma unroll
    for (int jc = 0; jc < 16; ++jc)
      xv[jc] = *(const uint2*)(xp + (size_t)(jb0 + jc) * 1024);
    if constexpr (CMODE == 1) {
#pragma unroll
      for (int jc = 0; jc < 16; ++jc) cv[jc] = cp[(size_t)(jb0 + jc) * 2048];
    }
    // ---- 8 j-pair MFMAs (slots 0-3 = even j, 4-7 = odd j; same map A and B)
#pragma unroll
    for (int jp = 0; jp < 8; ++jp) {
      const int ja = 2 * jp, jb2 = 2 * jp + 1;
      const short8v af = mk_frag4(wv[ja].x, wv[ja].y, wv[jb2].x, wv[jb2].y);
      short8v bf;
      if constexpr (CMODE == 1) {
        const float ca = cv[ja], cb = cv[jb2];
        const unsigned int p0 = f2bf(bf2f(xv[ja].x & 0xffffu) * ca) |
                                (f2bf(bf2f(xv[ja].x >> 16) * ca) << 16);
        const unsigned int p1 = f2bf(bf2f(xv[ja].y & 0xffffu) * ca) |
                                (f2bf(bf2f(xv[ja].y >> 16) * ca) << 16);
        const unsigned int p2 = f2bf(bf2f(xv[jb2].x & 0xffffu) * cb) |
                                (f2bf(bf2f(xv[jb2].x >> 16) * cb) << 16);
        const unsigned int p3 = f2bf(bf2f(xv[jb2].y & 0xffffu) * cb) |
                                (f2bf(bf2f(xv[jb2].y >> 16) * cb) << 16);
        bf = mk_frag4(p0, p1, p2, p3);
      } else {
        bf = mk_frag4(xv[ja].x, xv[ja].y, xv[jb2].x, xv[jb2].y);
      }
      acc = __builtin_amdgcn_mfma_f32_16x16x32_bf16(af, bf, acc, 0, 0, 0);
    }
  }
  const float sc = (CMODE == 0) ? (1.f / 32.f) : 1.f;
  // C layout: col = b (lane&15), row = d = 4g + reg  ->  16B contiguous store
  *(float4*)(spart + (((size_t)b * CHB + ch) * 32 + k) * 16 + 4 * g) =
      make_float4(acc[0] * sc, acc[1] * sc, acc[2] * sc, acc[3] * sc);
}

// ---------------- squash: reduce spart -> s, squash -> o; f32 osum master +
// bf16 osB mirror in k_A's fragment layout [k][bt][hi*32+b31][slot].
__global__ __launch_bounds__(256) void k_squash(const float* __restrict__ spart,
                                                float* __restrict__ osum,
                                                unsigned short* __restrict__ osB,
                                                float* __restrict__ outp,
                                                int first, int final_) {
  const int t = threadIdx.x;
  const int wave = t >> 6, lane = t & 63;
  const int gw = blockIdx.x * 4 + wave;   // 0..B_*K_-1
  const int b = gw >> 5, k = gw & 31;
  const int d = lane & 15, pg = lane >> 4;
  float s = 0.f;
#pragma unroll
  for (int p = pg; p < CHB; p += 4)
    s += spart[(((size_t)b * CHB + p) * 32 + k) * 16 + d];
  s += __shfl_xor(s, 16);
  s += __shfl_xor(s, 32);
  float ss = s * s;
  ss += __shfl_xor(ss, 1); ss += __shfl_xor(ss, 2);
  ss += __shfl_xor(ss, 4); ss += __shfl_xor(ss, 8);
  const float scale = (ss / (1.f + ss)) * rsqrtf(ss + 1e-7f);
  const float ov = scale * s;
  if (final_) {
    if (lane < 16) outp[((size_t)b * K_ + k) * 2064 + d] = ov;
  } else {
    const float prev = first ? 0.f : osum[b * KD + k * 16 + d];
    const float ns = prev + ov;
    if (lane < 16) {
      osum[b * KD + k * 16 + d] = ns;
      // osB scatter: d -> (hi, slot): hi = (d>>2)&1, slot = (d&3) + 4*(d>>3)
      const int hi = (d >> 2) & 1;
      const int slot = (d & 3) + ((d >> 3) << 2);
      osB[(((size_t)k * 2 + (b >> 5)) * 64 + hi * 32 + (b & 31)) * 8 + slot] = f2bf(ns);
    }
  }
}

extern "C" void kernel_launch(void* const* d_in, const int* in_sizes, int n_in,
                              void* d_out, int out_size, void* d_ws, size_t ws_size,
                              hipStream_t stream) {
  const float* inp = (const float*)d_in[0];   // [64,2048,16]
  const float* W   = (const float*)d_in[1];   // [32,2048,16,16]
  float* outp = (float*)d_out;                // [64,32,2064]
  char* ws = (char*)d_ws;
  // ws: WB 32M | XT 4M | cT 16M | spart region 16M (4M used) | osum 128K | osB 64K
  unsigned short* WB = (unsigned short*)ws;
  unsigned short* XT = (unsigned short*)(ws + (size_t)33554432);
  float* cT    = (float*)(ws + (size_t)33554432 + 4194304);
  float* spart = (float*)(ws + (size_t)33554432 + 4194304 + 16777216);
  float* osum  = (float*)(ws + (size_t)33554432 + 4194304 + 16777216 + 16777216);
  unsigned short* osB =
      (unsigned short*)(ws + (size_t)33554432 + 4194304 + 16777216 + 16777216 + 131072);

  k_prep<<<2048, 256, 0, stream>>>(inp, W, WB, XT);
  // iter 0: c = 1/32
  k_B<0><<<CHB * K_, 256, 0, stream>>>(XT, WB, nullptr, spart);
  k_squash<<<B_ * K_ / 4, 256, 0, stream>>>(spart, osum, osB, outp, 1, 0);
  // iter 1
  k_A<<<J_ / 4, 256, 0, stream>>>(XT, WB, osB, cT);
  k_B<1><<<CHB * K_, 256, 0, stream>>>(XT, WB, cT, spart);
  k_squash<<<B_ * K_ / 4, 256, 0, stream>>>(spart, osum, osB, outp, 0, 0);
  // iter 2 (final)
  k_A<<<J_ / 4, 256, 0, stream>>>(XT, WB, osB, cT);
  k_cout<<<K_ * 16, 256, 0, stream>>>(cT, outp);
  k_B<1><<<CHB * K_, 256, 0, stream>>>(XT, WB, cT, spart);
  k_squash<<<B_ * K_ / 4, 256, 0, stream>>>(spart, osum, osB, outp, 0, 1);
}

// Round 12
// 121.060 us; speedup vs baseline: 2.1054x; 1.0347x over previous
//
#include <hip/hip_runtime.h>
#include <hip/hip_bf16.h>

#define B_ 64
#define J_ 2048
#define K_ 32
#define D_ 16
#define KD 512
#define CHB 32       // k_B j-chunks (spart partials)
#define JCB 64       // j's per k_B chunk

typedef __attribute__((ext_vector_type(8))) short short8v;    // 8 bf16 (4 VGPR)
typedef __attribute__((ext_vector_type(4))) float f32x4;      // 4 f32 acc
typedef __attribute__((ext_vector_type(16))) float f32x16;    // 16 f32 acc (32x32)

__device__ __forceinline__ float bf2f(unsigned int bits16) {
  unsigned int u = bits16 << 16;
  return __builtin_bit_cast(float, u);
}
__device__ __forceinline__ unsigned int f2bf(float f) {
  unsigned int u = __builtin_bit_cast(unsigned int, f);
  u = u + 0x7fffu + ((u >> 16) & 1u);   // round-to-nearest-even
  return u >> 16;
}
// HW packed f32->bf16 pair convert (gfx950; no builtin -- inline asm). lo -> low16.
__device__ __forceinline__ unsigned int cvtpk(float lo, float hi) {
  unsigned int r;
  asm("v_cvt_pk_bf16_f32 %0, %1, %2" : "=v"(r) : "v"(lo), "v"(hi));
  return r;
}
// (bf16,bf16) dword * scalar c -> (bf16,bf16) dword
__device__ __forceinline__ unsigned int pkmul(unsigned int w, float c) {
  const float lo = __builtin_bit_cast(float, w << 16) * c;
  const float hi = __builtin_bit_cast(float, w & 0xffff0000u) * c;
  return cvtpk(lo, hi);
}
__device__ __forceinline__ short8v mk_frag4(unsigned int d0, unsigned int d1,
                                            unsigned int d2, unsigned int d3) {
  uint4 t = make_uint4(d0, d1, d2, d3);        // slots 0-3 = j0, 4-7 = j1
  return __builtin_bit_cast(short8v, t);
}
__device__ __forceinline__ f32x16 zero16() {
  f32x16 z;
#pragma unroll
  for (int i = 0; i < 16; ++i) z[i] = 0.f;
  return z;
}

// ---------------- prepX: XT[j][b][i] = bf16(x[b][j][i])  (x transpose+convert only)
__global__ __launch_bounds__(256) void k_prepX(const float* __restrict__ inp,
                                               unsigned short* __restrict__ XT) {
  const size_t tid = (size_t)blockIdx.x * 256 + threadIdx.x;
  const size_t stride = (size_t)gridDim.x * 256;
  for (size_t g8 = tid; g8 < (size_t)J_ * B_ * 2; g8 += stride) {
    const size_t o = g8 * 8;
    const int j = (int)(o >> 10), b = (int)((o >> 4) & 63), i0 = (int)(o & 15);
    const float* src = inp + ((size_t)b * J_ + j) * 16 + i0;
    const float4 a = *(const float4*)src;
    const float4 c = *(const float4*)(src + 4);
    uint4 pk;
    pk.x = cvtpk(a.x, a.y);
    pk.y = cvtpk(a.z, a.w);
    pk.z = cvtpk(c.x, c.y);
    pk.w = cvtpk(c.z, c.w);
    *(uint4*)(XT + o) = pk;
  }
}

// ---------------- k_B0: iter-0 s-partials (c = 1/32) FUSED with W->bf16 conversion.
// Reads W f32 directly (one pass over all of W), writes WB[j][k][d][i] bf16 as a
// side-product for k_A / k_B1, and accumulates its MFMA chain from the converted regs.
__global__ __launch_bounds__(256, 4) void k_B0(const float* __restrict__ W,
                                               const unsigned short* __restrict__ XT,
                                               unsigned short* __restrict__ WB,
                                               float* __restrict__ spart) {
  const int x = blockIdx.x;
  const int ch = x >> 5, k = x & 31;
  const int t = threadIdx.x;
  const int wave = t >> 6, lane = t & 63;
  const int g = lane >> 4, r = lane & 15;
  const int b = wave * 16 + r;
  const int j0 = ch * JCB;

  // W[k][j][d][i] f32: thread's 4 floats at (k*J+j)*256 + r*16 + 4g  (d = r)
  const float* wpF = W + ((size_t)k * J_ + j0) * 256 + r * 16 + 4 * g;
  unsigned short* wq = WB + ((size_t)j0 * 32 + k) * 256 + r * 16 + 4 * g;
  const unsigned short* xp = XT + ((size_t)j0 * 64 + b) * 16 + 4 * g;

  f32x4 acc = {0.f, 0.f, 0.f, 0.f};
#pragma unroll
  for (int batch = 0; batch < 8; ++batch) {
    const int jb0 = batch * 8;
    float4 wF[8];
    uint2 xv[8];
#pragma unroll
    for (int jc = 0; jc < 8; ++jc)
      wF[jc] = *(const float4*)(wpF + (size_t)(jb0 + jc) * 256);
#pragma unroll
    for (int jc = 0; jc < 8; ++jc)
      xv[jc] = *(const uint2*)(xp + (size_t)(jb0 + jc) * 1024);
    uint2 wv[8];
#pragma unroll
    for (int jc = 0; jc < 8; ++jc) {
      wv[jc].x = cvtpk(wF[jc].x, wF[jc].y);
      wv[jc].y = cvtpk(wF[jc].z, wF[jc].w);
      *(uint2*)(wq + (size_t)(jb0 + jc) * 8192) = wv[jc];    // WB side-product
    }
#pragma unroll
    for (int jp = 0; jp < 4; ++jp) {
      const int ja = 2 * jp, jb2 = 2 * jp + 1;
      acc = __builtin_amdgcn_mfma_f32_16x16x32_bf16(
          mk_frag4(wv[ja].x, wv[ja].y, wv[jb2].x, wv[jb2].y),
          mk_frag4(xv[ja].x, xv[ja].y, xv[jb2].x, xv[jb2].y), acc, 0, 0, 0);
    }
  }
  // C layout: col = b (lane&15), row = d = 4g + reg  ->  16B contiguous store
  *(float4*)(spart + (((size_t)b * CHB + ch) * 32 + k) * 16 + 4 * g) =
      make_float4(acc[0] * (1.f / 32.f), acc[1] * (1.f / 32.f),
                  acc[2] * (1.f / 32.f), acc[3] * (1.f / 32.f));
}

// ---------------- k_A (32x32 MFMA): c[j][k][b] = softmax_k(osum . u_hat) directly.
// Block = 4 j's, grid 512. Wave = (jg, bt) handles 2 j's; os loaded+decoded once per
// k-pair, reused by both j. In-register softmax over 32 k; direct c store.
__global__ __launch_bounds__(256, 2) void k_A(const unsigned short* __restrict__ XT,
                                              const unsigned short* __restrict__ WB,
                                              const unsigned short* __restrict__ osB,
                                              float* __restrict__ cT) {
  const int jb = blockIdx.x;
  const int t = threadIdx.x;
  const int wave = t >> 6, lane = t & 63;
  const int jg = wave >> 1, bt = wave & 1;
  const int jB = jb * 4 + jg * 2;              // wave's j's: jB, jB+1
  const int hi = lane >> 5, b31 = lane & 31;
  const int b = bt * 32 + b31;

  short8v xf[2];
#pragma unroll
  for (int jj = 0; jj < 2; ++jj)
    xf[jj] = __builtin_bit_cast(short8v,
        *(const uint4*)(XT + (size_t)(jB + jj) * 1024 + b * 16 + 8 * hi));

  const unsigned short* wa0 =
      WB + (size_t)jB * 8192 + (b31 >> 4) * 256 + (b31 & 15) * 16 + 8 * hi;
  const unsigned short* osb = osB + ((size_t)bt * 64 + lane) * 8;   // + k*1024

  float S[2] = {0.f, 0.f};
  unsigned int e_pk[2][16];                    // bf16-packed e for k = 2tp, 2tp+1

#pragma unroll
  for (int grp = 0; grp < 4; ++grp) {
    uint4 os0[4], os1[4], av[2][4];
#pragma unroll
    for (int q = 0; q < 4; ++q) {
      const int tp = grp * 4 + q;
      os0[q] = *(const uint4*)(osb + (size_t)(2 * tp) * 1024);
      os1[q] = *(const uint4*)(osb + (size_t)(2 * tp + 1) * 1024);
      av[0][q] = *(const uint4*)(wa0 + (size_t)tp * 512);
      av[1][q] = *(const uint4*)(wa0 + 8192 + (size_t)tp * 512);
    }
#pragma unroll
    for (int q = 0; q < 4; ++q) {
      const int tp = grp * 4 + q;
      const unsigned int* o0 = (const unsigned int*)&os0[q];
      const unsigned int* o1 = (const unsigned int*)&os1[q];
      float f0v[8], f1v[8];
#pragma unroll
      for (int s = 0; s < 8; ++s) {
        const unsigned int w0 = o0[s >> 1], w1 = o1[s >> 1];
        f0v[s] = bf2f((s & 1) ? (w0 >> 16) : (w0 & 0xffffu));
        f1v[s] = bf2f((s & 1) ? (w1 >> 16) : (w1 & 0xffffu));
      }
#pragma unroll
      for (int jj = 0; jj < 2; ++jj) {
        const f32x16 u = __builtin_amdgcn_mfma_f32_32x32x16_bf16(
            __builtin_bit_cast(short8v, av[jj][q]), xf[jj], zero16(), 0, 0, 0);
        float pe = 0.f, po = 0.f;
#pragma unroll
        for (int s = 0; s < 8; ++s) {
          pe = fmaf(u[s], f0v[s], pe);       // regs 0-7: k even, d=(s&3)+4hi+8*(s>>2)
          po = fmaf(u[8 + s], f1v[s], po);   // regs 8-15: k odd
        }
        pe += __shfl_xor(pe, 32);            // partner hi-half: full dot over d
        po += __shfl_xor(po, 32);
        // logits O(+-8): skip max-subtraction (shift-invariant; validated r1-r11)
        const float ee = __expf(pe), eo = __expf(po);
        S[jj] += ee + eo;
        e_pk[jj][tp] = cvtpk(ee, eo);
      }
    }
  }

  if (hi == 0) {                             // lanes 0-31: b-contiguous 128B stores
#pragma unroll
    for (int jj = 0; jj < 2; ++jj) {
      const float rS = __builtin_amdgcn_rcpf(S[jj]);
      float* cp = cT + (size_t)(jB + jj) * 2048 + b;      // + k*64
#pragma unroll
      for (int tp = 0; tp < 16; ++tp) {
        cp[(size_t)(2 * tp) * 64]     = bf2f(e_pk[jj][tp] & 0xffffu) * rS;
        cp[(size_t)(2 * tp + 1) * 64] = bf2f(e_pk[jj][tp] >> 16) * rS;
      }
    }
  }
}

// ---------------- k_B1: s-partials via MFMA, c folded into B-frag (pkmul+cvt_pk).
// COUT=1: blocks >= 1024 instead run the c-transpose into outp (fused k_cout).
template <int COUT>
__global__ __launch_bounds__(256, 4) void k_B1(const unsigned short* __restrict__ XT,
                                               const unsigned short* __restrict__ WB,
                                               const float* __restrict__ cT,
                                               float* __restrict__ spart,
                                               float* __restrict__ outp) {
  __shared__ float lds[COUT ? 64 * 129 : 1];
  if (COUT && blockIdx.x >= 1024) {
    // ---- fused k_cout: cT[j][k][b] -> outp[b][k][16+j]
    const int bx = blockIdx.x - 1024;
    const int k = bx & 31, j0 = (bx >> 5) * 128;
    const int t = threadIdx.x;
#pragma unroll
    for (int m = 0; m < 32; ++m) {
      const int jj = m * 4 + (t >> 6), b = t & 63;
      lds[b * 129 + jj] = cT[((size_t)(j0 + jj) * 32 + k) * 64 + b];  // coalesced
    }
    __syncthreads();
#pragma unroll
    for (int m = 0; m < 8; ++m) {
      const int b = m * 8 + (t >> 5), jq = (t & 31) * 4;
      *(float4*)(outp + ((size_t)b * 32 + k) * 2064 + 16 + j0 + jq) =
          make_float4(lds[b * 129 + jq], lds[b * 129 + jq + 1],
                      lds[b * 129 + jq + 2], lds[b * 129 + jq + 3]);
    }
    return;
  }

  const int x = blockIdx.x;
  const int ch = x >> 5, k = x & 31;
  const int t = threadIdx.x;
  const int wave = t >> 6, lane = t & 63;
  const int g = lane >> 4, r = lane & 15;
  const int b = wave * 16 + r;
  const int j0 = ch * JCB;

  const unsigned short* wp = WB + ((size_t)j0 * 32 + k) * 256 + r * 16 + 4 * g;
  const unsigned short* xp = XT + ((size_t)j0 * 64 + b) * 16 + 4 * g;
  const float* cp = cT + ((size_t)j0 * 32 + k) * 64 + b;

  f32x4 acc = {0.f, 0.f, 0.f, 0.f};
#pragma unroll
  for (int batch = 0; batch < 4; ++batch) {
    const int jb0 = batch * 16;
    uint2 wv[16], xv[16];
    float cv[16];
#pragma unroll
    for (int jc = 0; jc < 16; ++jc)
      wv[jc] = *(const uint2*)(wp + (size_t)(jb0 + jc) * 8192);
#pragma unroll
    for (int jc = 0; jc < 16; ++jc)
      xv[jc] = *(const uint2*)(xp + (size_t)(jb0 + jc) * 1024);
#pragma unroll
    for (int jc = 0; jc < 16; ++jc) cv[jc] = cp[(size_t)(jb0 + jc) * 2048];
#pragma unroll
    for (int jp = 0; jp < 8; ++jp) {
      const int ja = 2 * jp, jb2 = 2 * jp + 1;
      const float ca = cv[ja], cb = cv[jb2];
      acc = __builtin_amdgcn_mfma_f32_16x16x32_bf16(
          mk_frag4(wv[ja].x, wv[ja].y, wv[jb2].x, wv[jb2].y),
          mk_frag4(pkmul(xv[ja].x, ca), pkmul(xv[ja].y, ca),
                   pkmul(xv[jb2].x, cb), pkmul(xv[jb2].y, cb)),
          acc, 0, 0, 0);
    }
  }
  *(float4*)(spart + (((size_t)b * CHB + ch) * 32 + k) * 16 + 4 * g) =
      make_float4(acc[0], acc[1], acc[2], acc[3]);
}

// ---------------- squash: reduce spart -> s, squash -> o; f32 osum master +
// bf16 osB mirror in k_A's fragment layout [k][bt][hi*32+b31][slot].
__global__ __launch_bounds__(256) void k_squash(const float* __restrict__ spart,
                                                float* __restrict__ osum,
                                                unsigned short* __restrict__ osB,
                                                float* __restrict__ outp,
                                                int first, int final_) {
  const int t = threadIdx.x;
  const int wave = t >> 6, lane = t & 63;
  const int gw = blockIdx.x * 4 + wave;   // 0..B_*K_-1
  const int b = gw >> 5, k = gw & 31;
  const int d = lane & 15, pg = lane >> 4;
  float s = 0.f;
#pragma unroll
  for (int p = pg; p < CHB; p += 4)
    s += spart[(((size_t)b * CHB + p) * 32 + k) * 16 + d];
  s += __shfl_xor(s, 16);
  s += __shfl_xor(s, 32);
  float ss = s * s;
  ss += __shfl_xor(ss, 1); ss += __shfl_xor(ss, 2);
  ss += __shfl_xor(ss, 4); ss += __shfl_xor(ss, 8);
  const float scale = (ss / (1.f + ss)) * rsqrtf(ss + 1e-7f);
  const float ov = scale * s;
  if (final_) {
    if (lane < 16) outp[((size_t)b * K_ + k) * 2064 + d] = ov;
  } else {
    const float prev = first ? 0.f : osum[b * KD + k * 16 + d];
    const float ns = prev + ov;
    if (lane < 16) {
      osum[b * KD + k * 16 + d] = ns;
      // osB scatter: d -> (hi, slot): hi = (d>>2)&1, slot = (d&3) + 4*(d>>3)
      const int hi = (d >> 2) & 1;
      const int slot = (d & 3) + ((d >> 3) << 2);
      osB[(((size_t)k * 2 + (b >> 5)) * 64 + hi * 32 + (b & 31)) * 8 + slot] = f2bf(ns);
    }
  }
}

extern "C" void kernel_launch(void* const* d_in, const int* in_sizes, int n_in,
                              void* d_out, int out_size, void* d_ws, size_t ws_size,
                              hipStream_t stream) {
  const float* inp = (const float*)d_in[0];   // [64,2048,16]
  const float* W   = (const float*)d_in[1];   // [32,2048,16,16]
  float* outp = (float*)d_out;                // [64,32,2064]
  char* ws = (char*)d_ws;
  // ws: WB 32M | XT 4M | cT 16M | spart 16M region | osum 128K | osB 64K
  unsigned short* WB = (unsigned short*)ws;
  unsigned short* XT = (unsigned short*)(ws + (size_t)33554432);
  float* cT    = (float*)(ws + (size_t)33554432 + 4194304);
  float* spart = (float*)(ws + (size_t)33554432 + 4194304 + 16777216);
  float* osum  = (float*)(ws + (size_t)33554432 + 4194304 + 16777216 + 16777216);
  unsigned short* osB =
      (unsigned short*)(ws + (size_t)33554432 + 4194304 + 16777216 + 16777216 + 131072);

  k_prepX<<<512, 256, 0, stream>>>(inp, XT);
  // iter 0: c = 1/32, fused with W->bf16 conversion (writes WB)
  k_B0<<<CHB * K_, 256, 0, stream>>>(W, XT, WB, spart);
  k_squash<<<B_ * K_ / 4, 256, 0, stream>>>(spart, osum, osB, outp, 1, 0);
  // iter 1
  k_A<<<J_ / 4, 256, 0, stream>>>(XT, WB, osB, cT);
  k_B1<0><<<CHB * K_, 256, 0, stream>>>(XT, WB, cT, spart, nullptr);
  k_squash<<<B_ * K_ / 4, 256, 0, stream>>>(spart, osum, osB, outp, 0, 0);
  // iter 2 (final): k_B1<1> also transposes c into outp (blocks >= 1024)
  k_A<<<J_ / 4, 256, 0, stream>>>(XT, WB, osB, cT);
  k_B1<1><<<CHB * K_ + 512, 256, 0, stream>>>(XT, WB, cT, spart, outp);
  k_squash<<<B_ * K_ / 4, 256, 0, stream>>>(spart, osum, osB, outp, 0, 1);
}